// Round 13
// baseline (125.167 us; speedup 1.0000x reference)
//
#include <hip/hip_runtime.h>

// Fused causal MHA on gfx950.  Pipeline (R12 = R9 + dynamic-queue persistent flash):
//   Flash: 1024 persistent blocks (4/CU), 256 thr.  Items (hb,qi) popped from a
//   global atomic counter, longest-first (idx -> qi=63-idx/24, hb=idx%24).
//   Counter zeroed via hipMemsetAsync before launch (graph-safe, replay-safe).
//   Body = R9 verified: QBLK=32, 4 waves split KV, swapped-operand MFMA
//   (mfma(K,Q)=S^T, mfma(V^T,P)=O^T), fixed-max softmax P=exp2(st), V first,
//   K prefetch under PV.
//
// ws: xb/zb @0 (6291456) | qkvb @6291456 (18874368) | vtb @25165824 (6291456)
//     wqkvT @31457280 (3538944) | woT @34996224 (1179648) | counter @36175872 (4)

#define DEVINL __device__ __forceinline__

using bf16x8 = __attribute__((ext_vector_type(8))) __bf16;
using f32x4  = __attribute__((ext_vector_type(4))) float;

DEVINL unsigned short f32_bf16(float f) {
    unsigned u = __builtin_bit_cast(unsigned, f);
    return (unsigned short)((u + 0x7FFFu + ((u >> 16) & 1u)) >> 16);
}

DEVINL void gload16(const void* g, void* l) {
    __builtin_amdgcn_global_load_lds(
        (const __attribute__((address_space(1))) void*)g,
        (__attribute__((address_space(3))) void*)l, 16, 0, 0);
}

// ---------------- fused prep: convert + weight transposes ----------------
__global__ __launch_bounds__(256) void k_prep(const float* __restrict__ x,
                                              const float* __restrict__ Wq,
                                              const float* __restrict__ Wk,
                                              const float* __restrict__ Wv,
                                              const float* __restrict__ Wo,
                                              unsigned short* __restrict__ xb,
                                              unsigned short* __restrict__ wqkvT,
                                              unsigned short* __restrict__ woT) {
    __shared__ unsigned short tl[64][68];
    const int bid = blockIdx.x;
    const int t = threadIdx.x;
    if (bid < 3072) {
        int i = (bid * 256 + t) * 4;
        float4 v = *(const float4*)(x + i);
        ushort4 o;
        o.x = f32_bf16(v.x); o.y = f32_bf16(v.y); o.z = f32_bf16(v.z); o.w = f32_bf16(v.w);
        *(ushort4*)(xb + i) = o;
        return;
    }
    const int c = t & 63, r0 = t >> 6;
    if (bid < 3504) {
        const int sub = bid - 3072;          // 0..431
        const int tr = sub % 12, batch = sub / 12;   // batch 0..35
        const float* src = (batch < 12) ? Wq : (batch < 24) ? Wk : Wv;
        src += (size_t)(batch % 12) * 768 * 64;
        unsigned short* out = wqkvT + (size_t)batch * 64 * 768;
#pragma unroll
        for (int k = 0; k < 16; ++k) {
            int r = k * 4 + r0;
            tl[r][c] = f32_bf16(src[(size_t)(tr * 64 + r) * 64 + c]);
        }
        __syncthreads();
#pragma unroll
        for (int k = 0; k < 16; ++k) {
            int r2 = k * 4 + r0;
            out[(size_t)r2 * 768 + tr * 64 + c] = tl[c][r2];
        }
    } else {
        const int sub = bid - 3504;          // 0..143
        const int tr = sub % 12, tc = sub / 12;
#pragma unroll
        for (int k = 0; k < 16; ++k) {
            int r = k * 4 + r0;
            tl[r][c] = f32_bf16(Wo[(size_t)(tr * 64 + r) * 768 + tc * 64 + c]);
        }
        __syncthreads();
#pragma unroll
        for (int k = 0; k < 16; ++k) {
            int r2 = k * 4 + r0;
            woT[(size_t)(tc * 64 + r2) * 768 + tr * 64 + c] = tl[c][r2];
        }
    }
}

// ---------------- transpose V: qkvb v-cols [b,s,2304] -> vtb [b*12+h][64][2048] -------
__global__ __launch_bounds__(256) void k_transpose_v(const unsigned short* __restrict__ vb,
                                                     unsigned short* __restrict__ vtb) {
    __shared__ unsigned short tl[64][68];
    const int bh = blockIdx.y;
    const int s0 = blockIdx.x * 64;
    const unsigned short* in = vb + ((size_t)((bh / 12) * 2048 + s0)) * 2304 + (bh % 12) * 64;
    unsigned short* outp = vtb + (size_t)bh * 64 * 2048 + s0;
    const int t = threadIdx.x, c = t & 63, r0 = t >> 6;
#pragma unroll
    for (int k = 0; k < 16; ++k) {
        int r = k * 4 + r0;
        tl[r][c] = in[(size_t)r * 2304 + c];
    }
    __syncthreads();
#pragma unroll
    for (int k = 0; k < 16; ++k) {
        int r2 = k * 4 + r0;
        outp[(size_t)r2 * 2048 + c] = tl[c][r2];
    }
}

// ---------------- GEMM: C[4096][N] = A[4096][768] @ BT[N][768] + bias ----------------
// 2-phase double-buffered global_load_lds staging, one barrier per K-step.
template <int BM, int BN, bool QKV>
__global__ __launch_bounds__(256) void k_gemm(const unsigned short* __restrict__ A,
                                              const unsigned short* __restrict__ BT,
                                              const float* __restrict__ b0,
                                              const float* __restrict__ b1,
                                              const float* __restrict__ b2,
                                              unsigned short* __restrict__ outb,
                                              float* __restrict__ outf) {
    constexpr int LDC = QKV ? 2304 : 768;
    constexpr int WM = BM / 2, WN = BN / 2, MR = WM / 16, NR = WN / 16;
    __shared__ alignas(16) unsigned short As[2][BM * 32];
    __shared__ alignas(16) unsigned short Bs[2][BN * 32];
    const int t = threadIdx.x;
    const int w = t >> 6, l = t & 63, lr = l & 15, lg = l >> 4;
    const int wr = (w >> 1) * WM, wc = (w & 1) * WN;
    const int m0 = blockIdx.y * BM;
    const int n0 = blockIdx.x * BN;

    auto stage = [&](int buf, int kt) {
        const int k0 = kt * 32;
#pragma unroll
        for (int i = 0; i < BM / 64; ++i) {
            const int s = i * 256 + t;
            gload16((const char*)A + ((size_t)(m0 + (s >> 2)) * 768 + k0) * 2 + (s & 3) * 16,
                    (char*)As[buf] + s * 16);
        }
#pragma unroll
        for (int i = 0; i < BN / 64; ++i) {
            const int s = i * 256 + t;
            gload16((const char*)BT + ((size_t)(n0 + (s >> 2)) * 768 + k0) * 2 + (s & 3) * 16,
                    (char*)Bs[buf] + s * 16);
        }
    };

    stage(0, 0);
    __syncthreads();

    f32x4 acc[MR][NR] = {};

    for (int kt = 0; kt < 24; ++kt) {
        const int cur = kt & 1;
        if (kt < 23) stage(cur ^ 1, kt + 1);

        bf16x8 af[MR], bfr[NR];
#pragma unroll
        for (int ri = 0; ri < MR; ++ri)
            af[ri] = *(const bf16x8*)&As[cur][(wr + ri * 16 + lr) * 32 + lg * 8];
#pragma unroll
        for (int cj = 0; cj < NR; ++cj)
            bfr[cj] = *(const bf16x8*)&Bs[cur][(wc + cj * 16 + lr) * 32 + lg * 8];
        __builtin_amdgcn_s_setprio(1);
#pragma unroll
        for (int ri = 0; ri < MR; ++ri)
#pragma unroll
            for (int cj = 0; cj < NR; ++cj)
                acc[ri][cj] = __builtin_amdgcn_mfma_f32_16x16x32_bf16(
                    af[ri], bfr[cj], acc[ri][cj], 0, 0, 0);
        __builtin_amdgcn_s_setprio(0);
        __syncthreads();
    }

#pragma unroll
    for (int cj = 0; cj < NR; ++cj) {
        const int col = n0 + wc + cj * 16 + lr;
        const float* bp = b0;
        int cc = col;
        if (QKV) {
            if (col >= 1536)      { bp = b2; cc = col - 1536; }
            else if (col >= 768)  { bp = b1; cc = col - 768; }
        }
        const float bv = bp[cc];
        const float scl = (QKV && col < 768) ? 0.18033688011112042f : 1.0f;  // 0.125*log2e
#pragma unroll
        for (int ri = 0; ri < MR; ++ri)
#pragma unroll
            for (int e = 0; e < 4; ++e) {
                const int row = m0 + wr + ri * 16 + lg * 4 + e;
                const float v = (acc[ri][cj][e] + bv) * scl;
                if (QKV) outb[(size_t)row * LDC + col] = f32_bf16(v);
                else     outf[(size_t)row * LDC + col] = v;
            }
    }
}

// ---------------- flash attention: persistent blocks + dynamic work queue -------------
// 1024 persistent blocks pop items from cnt.  Item idx: hb=idx%24, qi=63-(idx/24)
// (longest first).  Body identical to R9's verified kernel.
#define WREG 8704
__global__ __launch_bounds__(256) void k_flash(const unsigned short* __restrict__ qkv,
                                               const unsigned short* __restrict__ vtb,
                                               unsigned short* __restrict__ zb,
                                               unsigned int* __restrict__ cnt) {
    __shared__ alignas(16) char smem[4 * WREG + 512];
    __shared__ int idx_sh;
    const int t = threadIdx.x, w = t >> 6, l = t & 63, lr = l & 15, lg = l >> 4;

    char* p_w = smem + w * WREG;                      // P[q][kv] bf16, swizzled
    float* llds = (float*)(smem + 4 * WREG);          // [4][32] row sums per wave

    for (;;) {
        if (t == 0) idx_sh = (int)atomicAdd(cnt, 1u);
        __syncthreads();   // publish idx; also fences prev item's LDS reads vs new writes
        const int j = idx_sh;
        if (j >= 1536) break;

        const int hb = j % 24;
        const int h = hb % 12, b = hb / 12;
        const int qi = 63 - (j / 24);
        const int q0 = qi * 32;
        const int nkv = (qi >> 1) + 1;

        const size_t qrowbase = (size_t)(b * 2048) * 2304;
        bf16x8 qf[2][2];
#pragma unroll
        for (int ri = 0; ri < 2; ++ri)
#pragma unroll
            for (int kk = 0; kk < 2; ++kk)
                qf[ri][kk] = *(const bf16x8*)(qkv + qrowbase +
                                              (size_t)(q0 + ri * 16 + lr) * 2304 +
                                              h * 64 + kk * 32 + lg * 8);

        f32x4 o[2][4] = {};        // O^T: o[ri][dj][e]: row d=dj*16+lg*4+e, col q=ri*16+lr
        float ls[2] = {0.f, 0.f};  // per-lane partial denominators

        const unsigned short* kb = qkv + qrowbase + 768 + h * 64;     // K cols
        const unsigned short* vt = vtb + (size_t)(b * 12 + h) * 64 * 2048;

        if (w < nkv) {
            bf16x8 kf[4][2];
            auto loadK = [&](int kv0) {
#pragma unroll
                for (int cj = 0; cj < 4; ++cj)
#pragma unroll
                    for (int kk = 0; kk < 2; ++kk)
                        kf[cj][kk] = *(const bf16x8*)(kb + (size_t)(kv0 + cj * 16 + lr) * 2304 +
                                                      kk * 32 + lg * 8);
            };

            int kt = w;
            loadK(kt * 64);
            do {
                const int kv0 = kt * 64;

                // V fragments issued FIRST (independent of S) -> latency covered
                bf16x8 vf[2][4];
#pragma unroll
                for (int kk = 0; kk < 2; ++kk)
#pragma unroll
                    for (int dj = 0; dj < 4; ++dj)
                        vf[kk][dj] = *(const bf16x8*)(vt + (size_t)(dj * 16 + lr) * 2048 +
                                                      kv0 + kk * 32 + lg * 8);

                // S^T: st[ri][cj][e] = S[q0+ri*16+lr][kv0+cj*16+lg*4+e] (exp2 domain)
                f32x4 st[2][4];
                const f32x4 zz = {0.f, 0.f, 0.f, 0.f};
                __builtin_amdgcn_s_setprio(1);
#pragma unroll
                for (int ri = 0; ri < 2; ++ri)
#pragma unroll
                    for (int cj = 0; cj < 4; ++cj) {
                        f32x4 a0 = __builtin_amdgcn_mfma_f32_16x16x32_bf16(kf[cj][0], qf[ri][0], zz, 0, 0, 0);
                        st[ri][cj] = __builtin_amdgcn_mfma_f32_16x16x32_bf16(kf[cj][1], qf[ri][1], a0, 0, 0, 0);
                    }
                __builtin_amdgcn_s_setprio(0);

                if (kt == nkv - 1) {  // diagonal tile: mask kv > q
#pragma unroll
                    for (int ri = 0; ri < 2; ++ri)
#pragma unroll
                        for (int cj = 0; cj < 4; ++cj)
#pragma unroll
                            for (int e = 0; e < 4; ++e) {
                                const int kvv = kv0 + cj * 16 + lg * 4 + e;
                                const int qq  = q0 + ri * 16 + lr;
                                if (kvv > qq) st[ri][cj][e] = -1e30f;
                            }
                }

                // fixed-max softmax: P = exp2(st); per-lane partial sums
#pragma unroll
                for (int ri = 0; ri < 2; ++ri) {
                    float ps = 0.f;
#pragma unroll
                    for (int cj = 0; cj < 4; ++cj)
#pragma unroll
                        for (int e = 0; e < 4; ++e) {
                            const float p = __builtin_amdgcn_exp2f(st[ri][cj][e]);
                            st[ri][cj][e] = p;
                            ps += p;
                        }
                    ls[ri] += ps;

                    const int row = ri * 16 + lr;
#pragma unroll
                    for (int cj = 0; cj < 4; ++cj) {
                        unsigned lo, hi;
                        asm("v_cvt_pk_bf16_f32 %0, %1, %2"
                            : "=v"(lo) : "v"(st[ri][cj][0]), "v"(st[ri][cj][1]));
                        asm("v_cvt_pk_bf16_f32 %0, %1, %2"
                            : "=v"(hi) : "v"(st[ri][cj][2]), "v"(st[ri][cj][3]));
                        const int gr = (cj * 2 + (lg >> 1)) ^ (lr & 7);
                        uint2 pk2; pk2.x = lo; pk2.y = hi;
                        *(uint2*)(p_w + row * 128 + gr * 16 + (lg & 1) * 8) = pk2;
                    }
                }

                // fence: P-stores must not be reordered past the pa loads below
                asm volatile("" ::: "memory");

                // prefetch next K tile under PV
                const bool more = (kt + 4 < nkv);
                if (more) loadK(kv0 + 256);

                __builtin_amdgcn_s_setprio(1);
#pragma unroll
                for (int kk = 0; kk < 2; ++kk)
#pragma unroll
                    for (int ri = 0; ri < 2; ++ri) {
                        const int row = ri * 16 + lr;
                        const int g = (kk * 4 + lg) ^ (lr & 7);
                        bf16x8 pa = *(const bf16x8*)(p_w + row * 128 + g * 16);
#pragma unroll
                        for (int dj = 0; dj < 4; ++dj)
                            o[ri][dj] = __builtin_amdgcn_mfma_f32_16x16x32_bf16(
                                vf[kk][dj], pa, o[ri][dj], 0, 0, 0);
                    }
                __builtin_amdgcn_s_setprio(0);

                // fence: next iteration's P-stores must not be hoisted above pa loads
                asm volatile("" ::: "memory");

                kt += 4;
            } while (kt < nkv);
        }

        // ---- row-total denominators ----
#pragma unroll
        for (int ri = 0; ri < 2; ++ri) {
            float ps = ls[ri];
            ps += __shfl_xor(ps, 16);
            ps += __shfl_xor(ps, 32);
            ls[ri] = ps;
        }
        if (lg == 0) {
#pragma unroll
            for (int ri = 0; ri < 2; ++ri)
                llds[w * 32 + ri * 16 + lr] = ls[ri];
        }
        __syncthreads();

        // ---- merge: plain sums across the 4 wave partials ----
        float* o_w = (float*)(smem + w * WREG);  // [32][68] f32, reuses own p region
#pragma unroll
        for (int ri = 0; ri < 2; ++ri) {
            const int row = ri * 16 + lr;
#pragma unroll
            for (int dj = 0; dj < 4; ++dj)
                *(f32x4*)&o_w[row * 68 + dj * 16 + lg * 4] = o[ri][dj];
        }
        __syncthreads();

        {
            const int row = w * 8 + (l >> 3);
            const int c0 = (l & 7) * 8;
            const float lt = llds[row] + llds[32 + row] + llds[64 + row] + llds[96 + row];
            const float inv = 1.0f / lt;
            ushort4 pk[2];
#pragma unroll
            for (int half = 0; half < 2; ++half) {
                unsigned short u[4];
#pragma unroll
                for (int k = 0; k < 4; ++k) {
                    float acc = 0.f;
#pragma unroll
                    for (int s = 0; s < 4; ++s)
                        acc += ((const float*)(smem + s * WREG))[row * 68 + c0 + half * 4 + k];
                    u[k] = f32_bf16(acc * inv);
                }
                pk[half] = make_ushort4(u[0], u[1], u[2], u[3]);
            }
            unsigned short* dst = zb + (size_t)(b * 2048 + q0 + row) * 768 + h * 64 + c0;
            *(ushort4*)dst = pk[0];
            *(ushort4*)(dst + 4) = pk[1];
        }
    }
}

extern "C" void kernel_launch(void* const* d_in, const int* in_sizes, int n_in,
                              void* d_out, int out_size, void* d_ws, size_t ws_size,
                              hipStream_t stream) {
    (void)in_sizes; (void)n_in; (void)out_size; (void)ws_size;
    const float* x   = (const float*)d_in[0];
    const float* W_Q = (const float*)d_in[1];
    const float* W_K = (const float*)d_in[2];
    const float* W_V = (const float*)d_in[3];
    const float* b_Q = (const float*)d_in[4];
    const float* b_K = (const float*)d_in[5];
    const float* b_V = (const float*)d_in[6];
    const float* W_O = (const float*)d_in[7];
    const float* b_O = (const float*)d_in[8];
    float* out = (float*)d_out;

    char* ws = (char*)d_ws;
    unsigned short* xb    = (unsigned short*)(ws);
    unsigned short* qkvb  = (unsigned short*)(ws + 6291456);
    unsigned short* vtb   = (unsigned short*)(ws + 25165824);
    unsigned short* wqkvT = (unsigned short*)(ws + 31457280);
    unsigned short* woT   = (unsigned short*)(ws + 34996224);
    unsigned int*   cnt   = (unsigned int*)(ws + 36175872);
    unsigned short* zb    = xb;  // xb dead after the QKV GEMM

    k_prep<<<3648, 256, 0, stream>>>(x, W_Q, W_K, W_V, W_O, xb, wqkvT, woT);

    k_gemm<128, 128, true><<<dim3(18, 32), 256, 0, stream>>>(xb, wqkvT, b_Q, b_K, b_V, qkvb, nullptr);

    k_transpose_v<<<dim3(32, 24), 256, 0, stream>>>(qkvb + 1536, vtb);

    hipMemsetAsync(cnt, 0, 4, stream);   // reset work-queue counter (graph-capturable)
    k_flash<<<1024, 256, 0, stream>>>(qkvb, vtb, zb, cnt);

    k_gemm<64, 64, false><<<dim3(12, 64), 256, 0, stream>>>(zb, woT, b_O, b_O, b_O, nullptr, out);
}

// Round 14
// 109.144 us; speedup vs baseline: 1.1468x; 1.1468x over previous
//
#include <hip/hip_runtime.h>

// Fused causal MHA on gfx950.  Pipeline (R13 = R9 + shared-prefix paired flash):
//   Flash: grid (24 bh, 32 pairs) = 768 UNIFORM blocks.  Pair p: item A (qiA=32+p)
//   and item B (qiB=31-p), same (b,h).  B's KV range is a prefix of A's and
//   nkvA+nkvB=33 always -> block loads only A's K/V tiles; B rides along free for
//   its prefix.  Per tile: B(QK,softmax,PV) then A(QK,softmax,[prefetch],PV).
//   Fixed-max softmax P=exp2(st); swapped-operand MFMA; V loads first.
//   All blocks equal work -> no causal tail; static map keeps R9's L2 locality.
//
// ws: xb/zb @0 (6291456) | qkvb @6291456 (18874368) | vtb @25165824 (6291456)
//     wqkvT @31457280 (3538944) | woT @34996224 (1179648)   total 36175872 B

#define DEVINL __device__ __forceinline__

using bf16x8 = __attribute__((ext_vector_type(8))) __bf16;
using f32x4  = __attribute__((ext_vector_type(4))) float;

DEVINL unsigned short f32_bf16(float f) {
    unsigned u = __builtin_bit_cast(unsigned, f);
    return (unsigned short)((u + 0x7FFFu + ((u >> 16) & 1u)) >> 16);
}

DEVINL void gload16(const void* g, void* l) {
    __builtin_amdgcn_global_load_lds(
        (const __attribute__((address_space(1))) void*)g,
        (__attribute__((address_space(3))) void*)l, 16, 0, 0);
}

// ---------------- fused prep: convert + weight transposes ----------------
__global__ __launch_bounds__(256) void k_prep(const float* __restrict__ x,
                                              const float* __restrict__ Wq,
                                              const float* __restrict__ Wk,
                                              const float* __restrict__ Wv,
                                              const float* __restrict__ Wo,
                                              unsigned short* __restrict__ xb,
                                              unsigned short* __restrict__ wqkvT,
                                              unsigned short* __restrict__ woT) {
    __shared__ unsigned short tl[64][68];
    const int bid = blockIdx.x;
    const int t = threadIdx.x;
    if (bid < 3072) {
        int i = (bid * 256 + t) * 4;
        float4 v = *(const float4*)(x + i);
        ushort4 o;
        o.x = f32_bf16(v.x); o.y = f32_bf16(v.y); o.z = f32_bf16(v.z); o.w = f32_bf16(v.w);
        *(ushort4*)(xb + i) = o;
        return;
    }
    const int c = t & 63, r0 = t >> 6;
    if (bid < 3504) {
        const int sub = bid - 3072;          // 0..431
        const int tr = sub % 12, batch = sub / 12;   // batch 0..35
        const float* src = (batch < 12) ? Wq : (batch < 24) ? Wk : Wv;
        src += (size_t)(batch % 12) * 768 * 64;
        unsigned short* out = wqkvT + (size_t)batch * 64 * 768;
#pragma unroll
        for (int k = 0; k < 16; ++k) {
            int r = k * 4 + r0;
            tl[r][c] = f32_bf16(src[(size_t)(tr * 64 + r) * 64 + c]);
        }
        __syncthreads();
#pragma unroll
        for (int k = 0; k < 16; ++k) {
            int r2 = k * 4 + r0;
            out[(size_t)r2 * 768 + tr * 64 + c] = tl[c][r2];
        }
    } else {
        const int sub = bid - 3504;          // 0..143
        const int tr = sub % 12, tc = sub / 12;
#pragma unroll
        for (int k = 0; k < 16; ++k) {
            int r = k * 4 + r0;
            tl[r][c] = f32_bf16(Wo[(size_t)(tr * 64 + r) * 768 + tc * 64 + c]);
        }
        __syncthreads();
#pragma unroll
        for (int k = 0; k < 16; ++k) {
            int r2 = k * 4 + r0;
            woT[(size_t)(tc * 64 + r2) * 768 + tr * 64 + c] = tl[c][r2];
        }
    }
}

// ---------------- transpose V: qkvb v-cols [b,s,2304] -> vtb [b*12+h][64][2048] -------
__global__ __launch_bounds__(256) void k_transpose_v(const unsigned short* __restrict__ vb,
                                                     unsigned short* __restrict__ vtb) {
    __shared__ unsigned short tl[64][68];
    const int bh = blockIdx.y;
    const int s0 = blockIdx.x * 64;
    const unsigned short* in = vb + ((size_t)((bh / 12) * 2048 + s0)) * 2304 + (bh % 12) * 64;
    unsigned short* outp = vtb + (size_t)bh * 64 * 2048 + s0;
    const int t = threadIdx.x, c = t & 63, r0 = t >> 6;
#pragma unroll
    for (int k = 0; k < 16; ++k) {
        int r = k * 4 + r0;
        tl[r][c] = in[(size_t)r * 2304 + c];
    }
    __syncthreads();
#pragma unroll
    for (int k = 0; k < 16; ++k) {
        int r2 = k * 4 + r0;
        outp[(size_t)r2 * 2048 + c] = tl[c][r2];
    }
}

// ---------------- GEMM: C[4096][N] = A[4096][768] @ BT[N][768] + bias ----------------
// 2-phase double-buffered global_load_lds staging, one barrier per K-step.
template <int BM, int BN, bool QKV>
__global__ __launch_bounds__(256) void k_gemm(const unsigned short* __restrict__ A,
                                              const unsigned short* __restrict__ BT,
                                              const float* __restrict__ b0,
                                              const float* __restrict__ b1,
                                              const float* __restrict__ b2,
                                              unsigned short* __restrict__ outb,
                                              float* __restrict__ outf) {
    constexpr int LDC = QKV ? 2304 : 768;
    constexpr int WM = BM / 2, WN = BN / 2, MR = WM / 16, NR = WN / 16;
    __shared__ alignas(16) unsigned short As[2][BM * 32];
    __shared__ alignas(16) unsigned short Bs[2][BN * 32];
    const int t = threadIdx.x;
    const int w = t >> 6, l = t & 63, lr = l & 15, lg = l >> 4;
    const int wr = (w >> 1) * WM, wc = (w & 1) * WN;
    const int m0 = blockIdx.y * BM;
    const int n0 = blockIdx.x * BN;

    auto stage = [&](int buf, int kt) {
        const int k0 = kt * 32;
#pragma unroll
        for (int i = 0; i < BM / 64; ++i) {
            const int s = i * 256 + t;
            gload16((const char*)A + ((size_t)(m0 + (s >> 2)) * 768 + k0) * 2 + (s & 3) * 16,
                    (char*)As[buf] + s * 16);
        }
#pragma unroll
        for (int i = 0; i < BN / 64; ++i) {
            const int s = i * 256 + t;
            gload16((const char*)BT + ((size_t)(n0 + (s >> 2)) * 768 + k0) * 2 + (s & 3) * 16,
                    (char*)Bs[buf] + s * 16);
        }
    };

    stage(0, 0);
    __syncthreads();

    f32x4 acc[MR][NR] = {};

    for (int kt = 0; kt < 24; ++kt) {
        const int cur = kt & 1;
        if (kt < 23) stage(cur ^ 1, kt + 1);

        bf16x8 af[MR], bfr[NR];
#pragma unroll
        for (int ri = 0; ri < MR; ++ri)
            af[ri] = *(const bf16x8*)&As[cur][(wr + ri * 16 + lr) * 32 + lg * 8];
#pragma unroll
        for (int cj = 0; cj < NR; ++cj)
            bfr[cj] = *(const bf16x8*)&Bs[cur][(wc + cj * 16 + lr) * 32 + lg * 8];
        __builtin_amdgcn_s_setprio(1);
#pragma unroll
        for (int ri = 0; ri < MR; ++ri)
#pragma unroll
            for (int cj = 0; cj < NR; ++cj)
                acc[ri][cj] = __builtin_amdgcn_mfma_f32_16x16x32_bf16(
                    af[ri], bfr[cj], acc[ri][cj], 0, 0, 0);
        __builtin_amdgcn_s_setprio(0);
        __syncthreads();
    }

#pragma unroll
    for (int cj = 0; cj < NR; ++cj) {
        const int col = n0 + wc + cj * 16 + lr;
        const float* bp = b0;
        int cc = col;
        if (QKV) {
            if (col >= 1536)      { bp = b2; cc = col - 1536; }
            else if (col >= 768)  { bp = b1; cc = col - 768; }
        }
        const float bv = bp[cc];
        const float scl = (QKV && col < 768) ? 0.18033688011112042f : 1.0f;  // 0.125*log2e
#pragma unroll
        for (int ri = 0; ri < MR; ++ri)
#pragma unroll
            for (int e = 0; e < 4; ++e) {
                const int row = m0 + wr + ri * 16 + lg * 4 + e;
                const float v = (acc[ri][cj][e] + bv) * scl;
                if (QKV) outb[(size_t)row * LDC + col] = f32_bf16(v);
                else     outf[(size_t)row * LDC + col] = v;
            }
    }
}

// ---------------- flash attention: shared-prefix paired items ----------------
// grid (hb=24, p=32), 256 thr.  Item A: qiA=32+p; item B: qiB=31-p (same b,h).
// nkvA in [17,32], nkvB = 33-nkvA.  B's KV range is a prefix of A's.
// Wave w handles tiles kt = w, w+4, ... of A's range; for kt<nkvB it also
// computes B on the SAME kf/vf registers.  Order per tile: B first, then A
// (kf last used by A-QK; K prefetch issued under A's PV as in R9).
#define WREG 8704
__global__ __launch_bounds__(256) void k_flash(const unsigned short* __restrict__ qkv,
                                               const unsigned short* __restrict__ vtb,
                                               unsigned short* __restrict__ zb) {
    __shared__ alignas(16) char smem[4 * WREG + 1024];
    const int hb = blockIdx.x;              // 0..23
    const int h = hb % 12, b = hb / 12;
    const int p = blockIdx.y;               // 0..31
    const int qiA = 32 + p, qiB = 31 - p;
    const int q0A = qiA * 32, q0B = qiB * 32;
    const int nkvA = (qiA >> 1) + 1, nkvB = (qiB >> 1) + 1;
    const int t = threadIdx.x, w = t >> 6, l = t & 63, lr = l & 15, lg = l >> 4;

    char* p_w = smem + w * WREG;                       // P[q][kv] bf16, swizzled
    float* lldsA = (float*)(smem + 4 * WREG);          // [4][32]
    float* lldsB = (float*)(smem + 4 * WREG + 512);    // [4][32]

    const size_t qrowbase = (size_t)(b * 2048) * 2304;
    bf16x8 qfA[2][2], qfB[2][2];
#pragma unroll
    for (int ri = 0; ri < 2; ++ri)
#pragma unroll
        for (int kk = 0; kk < 2; ++kk) {
            qfA[ri][kk] = *(const bf16x8*)(qkv + qrowbase +
                                           (size_t)(q0A + ri * 16 + lr) * 2304 +
                                           h * 64 + kk * 32 + lg * 8);
            qfB[ri][kk] = *(const bf16x8*)(qkv + qrowbase +
                                           (size_t)(q0B + ri * 16 + lr) * 2304 +
                                           h * 64 + kk * 32 + lg * 8);
        }

    f32x4 oA[2][4] = {}, oB[2][4] = {};
    float lsA[2] = {0.f, 0.f}, lsB[2] = {0.f, 0.f};

    const unsigned short* kb = qkv + qrowbase + 768 + h * 64;     // K cols
    const unsigned short* vt = vtb + (size_t)(b * 12 + h) * 64 * 2048;

    {
        bf16x8 kf[4][2];
        auto loadK = [&](int kv0) {
#pragma unroll
            for (int cj = 0; cj < 4; ++cj)
#pragma unroll
                for (int kk = 0; kk < 2; ++kk)
                    kf[cj][kk] = *(const bf16x8*)(kb + (size_t)(kv0 + cj * 16 + lr) * 2304 +
                                                  kk * 32 + lg * 8);
        };

        int kt = w;                // nkvA >= 17 > 4, so every wave has work
        loadK(kt * 64);
        do {
            const int kv0 = kt * 64;

            // V fragments issued FIRST -> latency covered by B+A compute
            bf16x8 vf[2][4];
#pragma unroll
            for (int kk = 0; kk < 2; ++kk)
#pragma unroll
                for (int dj = 0; dj < 4; ++dj)
                    vf[kk][dj] = *(const bf16x8*)(vt + (size_t)(dj * 16 + lr) * 2048 +
                                                  kv0 + kk * 32 + lg * 8);

            const f32x4 zz = {0.f, 0.f, 0.f, 0.f};

            // ================= item B (prefix rider) =================
            if (kt < nkvB) {
                f32x4 st[2][4];
                __builtin_amdgcn_s_setprio(1);
#pragma unroll
                for (int ri = 0; ri < 2; ++ri)
#pragma unroll
                    for (int cj = 0; cj < 4; ++cj) {
                        f32x4 a0 = __builtin_amdgcn_mfma_f32_16x16x32_bf16(kf[cj][0], qfB[ri][0], zz, 0, 0, 0);
                        st[ri][cj] = __builtin_amdgcn_mfma_f32_16x16x32_bf16(kf[cj][1], qfB[ri][1], a0, 0, 0, 0);
                    }
                __builtin_amdgcn_s_setprio(0);

                if (kt == nkvB - 1) {
#pragma unroll
                    for (int ri = 0; ri < 2; ++ri)
#pragma unroll
                        for (int cj = 0; cj < 4; ++cj)
#pragma unroll
                            for (int e = 0; e < 4; ++e) {
                                const int kvv = kv0 + cj * 16 + lg * 4 + e;
                                const int qq  = q0B + ri * 16 + lr;
                                if (kvv > qq) st[ri][cj][e] = -1e30f;
                            }
                }

#pragma unroll
                for (int ri = 0; ri < 2; ++ri) {
                    float ps = 0.f;
#pragma unroll
                    for (int cj = 0; cj < 4; ++cj)
#pragma unroll
                        for (int e = 0; e < 4; ++e) {
                            const float pv = __builtin_amdgcn_exp2f(st[ri][cj][e]);
                            st[ri][cj][e] = pv;
                            ps += pv;
                        }
                    lsB[ri] += ps;

                    const int row = ri * 16 + lr;
#pragma unroll
                    for (int cj = 0; cj < 4; ++cj) {
                        unsigned lo, hi;
                        asm("v_cvt_pk_bf16_f32 %0, %1, %2"
                            : "=v"(lo) : "v"(st[ri][cj][0]), "v"(st[ri][cj][1]));
                        asm("v_cvt_pk_bf16_f32 %0, %1, %2"
                            : "=v"(hi) : "v"(st[ri][cj][2]), "v"(st[ri][cj][3]));
                        const int gr = (cj * 2 + (lg >> 1)) ^ (lr & 7);
                        uint2 pk2; pk2.x = lo; pk2.y = hi;
                        *(uint2*)(p_w + row * 128 + gr * 16 + (lg & 1) * 8) = pk2;
                    }
                }

                asm volatile("" ::: "memory");

                __builtin_amdgcn_s_setprio(1);
#pragma unroll
                for (int kk = 0; kk < 2; ++kk)
#pragma unroll
                    for (int ri = 0; ri < 2; ++ri) {
                        const int row = ri * 16 + lr;
                        const int g = (kk * 4 + lg) ^ (lr & 7);
                        bf16x8 pa = *(const bf16x8*)(p_w + row * 128 + g * 16);
#pragma unroll
                        for (int dj = 0; dj < 4; ++dj)
                            oB[ri][dj] = __builtin_amdgcn_mfma_f32_16x16x32_bf16(
                                vf[kk][dj], pa, oB[ri][dj], 0, 0, 0);
                    }
                __builtin_amdgcn_s_setprio(0);

                asm volatile("" ::: "memory");
            }

            // ================= item A =================
            {
                f32x4 st[2][4];
                __builtin_amdgcn_s_setprio(1);
#pragma unroll
                for (int ri = 0; ri < 2; ++ri)
#pragma unroll
                    for (int cj = 0; cj < 4; ++cj) {
                        f32x4 a0 = __builtin_amdgcn_mfma_f32_16x16x32_bf16(kf[cj][0], qfA[ri][0], zz, 0, 0, 0);
                        st[ri][cj] = __builtin_amdgcn_mfma_f32_16x16x32_bf16(kf[cj][1], qfA[ri][1], a0, 0, 0, 0);
                    }
                __builtin_amdgcn_s_setprio(0);

                if (kt == nkvA - 1) {
#pragma unroll
                    for (int ri = 0; ri < 2; ++ri)
#pragma unroll
                        for (int cj = 0; cj < 4; ++cj)
#pragma unroll
                            for (int e = 0; e < 4; ++e) {
                                const int kvv = kv0 + cj * 16 + lg * 4 + e;
                                const int qq  = q0A + ri * 16 + lr;
                                if (kvv > qq) st[ri][cj][e] = -1e30f;
                            }
                }

#pragma unroll
                for (int ri = 0; ri < 2; ++ri) {
                    float ps = 0.f;
#pragma unroll
                    for (int cj = 0; cj < 4; ++cj)
#pragma unroll
                        for (int e = 0; e < 4; ++e) {
                            const float pv = __builtin_amdgcn_exp2f(st[ri][cj][e]);
                            st[ri][cj][e] = pv;
                            ps += pv;
                        }
                    lsA[ri] += ps;

                    const int row = ri * 16 + lr;
#pragma unroll
                    for (int cj = 0; cj < 4; ++cj) {
                        unsigned lo, hi;
                        asm("v_cvt_pk_bf16_f32 %0, %1, %2"
                            : "=v"(lo) : "v"(st[ri][cj][0]), "v"(st[ri][cj][1]));
                        asm("v_cvt_pk_bf16_f32 %0, %1, %2"
                            : "=v"(hi) : "v"(st[ri][cj][2]), "v"(st[ri][cj][3]));
                        const int gr = (cj * 2 + (lg >> 1)) ^ (lr & 7);
                        uint2 pk2; pk2.x = lo; pk2.y = hi;
                        *(uint2*)(p_w + row * 128 + gr * 16 + (lg & 1) * 8) = pk2;
                    }
                }

                asm volatile("" ::: "memory");

                // prefetch next K tile (kf dead after A-QK) under A's PV
                const bool more = (kt + 4 < nkvA);
                if (more) loadK(kv0 + 256);

                __builtin_amdgcn_s_setprio(1);
#pragma unroll
                for (int kk = 0; kk < 2; ++kk)
#pragma unroll
                    for (int ri = 0; ri < 2; ++ri) {
                        const int row = ri * 16 + lr;
                        const int g = (kk * 4 + lg) ^ (lr & 7);
                        bf16x8 pa = *(const bf16x8*)(p_w + row * 128 + g * 16);
#pragma unroll
                        for (int dj = 0; dj < 4; ++dj)
                            oA[ri][dj] = __builtin_amdgcn_mfma_f32_16x16x32_bf16(
                                vf[kk][dj], pa, oA[ri][dj], 0, 0, 0);
                    }
                __builtin_amdgcn_s_setprio(0);

                asm volatile("" ::: "memory");
            }

            kt += 4;
        } while (kt < nkvA);
    }

    // ---- row-total denominators for both items ----
#pragma unroll
    for (int ri = 0; ri < 2; ++ri) {
        float a = lsA[ri];
        a += __shfl_xor(a, 16); a += __shfl_xor(a, 32);
        lsA[ri] = a;
        float bsum = lsB[ri];
        bsum += __shfl_xor(bsum, 16); bsum += __shfl_xor(bsum, 32);
        lsB[ri] = bsum;
    }
    if (lg == 0) {
#pragma unroll
        for (int ri = 0; ri < 2; ++ri) {
            lldsA[w * 32 + ri * 16 + lr] = lsA[ri];
            lldsB[w * 32 + ri * 16 + lr] = lsB[ri];
        }
    }
    __syncthreads();   // loops done; P regions dead; llds complete

    // ---- merge item A, then item B (reusing scratch) ----
#pragma unroll
    for (int item = 0; item < 2; ++item) {
        const float* lld = item ? lldsB : lldsA;
        const int q0 = item ? q0B : q0A;
        float* o_w = (float*)(smem + w * WREG);  // [32][68] f32
#pragma unroll
        for (int ri = 0; ri < 2; ++ri) {
            const int row = ri * 16 + lr;
#pragma unroll
            for (int dj = 0; dj < 4; ++dj)
                *(f32x4*)&o_w[row * 68 + dj * 16 + lg * 4] = item ? oB[ri][dj] : oA[ri][dj];
        }
        __syncthreads();
        {
            const int row = w * 8 + (l >> 3);
            const int c0 = (l & 7) * 8;
            const float lt = lld[row] + lld[32 + row] + lld[64 + row] + lld[96 + row];
            const float inv = 1.0f / lt;
            ushort4 pk[2];
#pragma unroll
            for (int half = 0; half < 2; ++half) {
                unsigned short u[4];
#pragma unroll
                for (int k = 0; k < 4; ++k) {
                    float acc = 0.f;
#pragma unroll
                    for (int s = 0; s < 4; ++s)
                        acc += ((const float*)(smem + s * WREG))[row * 68 + c0 + half * 4 + k];
                    u[k] = f32_bf16(acc * inv);
                }
                pk[half] = make_ushort4(u[0], u[1], u[2], u[3]);
            }
            unsigned short* dst = zb + (size_t)(b * 2048 + q0 + row) * 768 + h * 64 + c0;
            *(ushort4*)dst = pk[0];
            *(ushort4*)(dst + 4) = pk[1];
        }
        __syncthreads();
    }
}

extern "C" void kernel_launch(void* const* d_in, const int* in_sizes, int n_in,
                              void* d_out, int out_size, void* d_ws, size_t ws_size,
                              hipStream_t stream) {
    (void)in_sizes; (void)n_in; (void)out_size; (void)ws_size;
    const float* x   = (const float*)d_in[0];
    const float* W_Q = (const float*)d_in[1];
    const float* W_K = (const float*)d_in[2];
    const float* W_V = (const float*)d_in[3];
    const float* b_Q = (const float*)d_in[4];
    const float* b_K = (const float*)d_in[5];
    const float* b_V = (const float*)d_in[6];
    const float* W_O = (const float*)d_in[7];
    const float* b_O = (const float*)d_in[8];
    float* out = (float*)d_out;

    char* ws = (char*)d_ws;
    unsigned short* xb    = (unsigned short*)(ws);
    unsigned short* qkvb  = (unsigned short*)(ws + 6291456);
    unsigned short* vtb   = (unsigned short*)(ws + 25165824);
    unsigned short* wqkvT = (unsigned short*)(ws + 31457280);
    unsigned short* woT   = (unsigned short*)(ws + 34996224);
    unsigned short* zb    = xb;  // xb dead after the QKV GEMM

    k_prep<<<3648, 256, 0, stream>>>(x, W_Q, W_K, W_V, W_O, xb, wqkvT, woT);

    k_gemm<128, 128, true><<<dim3(18, 32), 256, 0, stream>>>(xb, wqkvT, b_Q, b_K, b_V, qkvb, nullptr);

    k_transpose_v<<<dim3(32, 24), 256, 0, stream>>>(qkvb + 1536, vtb);
    k_flash<<<dim3(24, 32), 256, 0, stream>>>(qkvb, vtb, zb);
    k_gemm<64, 64, false><<<dim3(12, 64), 256, 0, stream>>>(zb, woT, b_O, b_O, b_O, nullptr, out);
}

// Round 15
// 109.091 us; speedup vs baseline: 1.1474x; 1.0005x over previous
//
#include <hip/hip_runtime.h>

// Fused causal MHA on gfx950.  Pipeline (R14 = R13 flash + fused V-transpose +
// QKV GEMM residency fix):
//   k_prep:  x fp32 -> xb bf16 ; W_Q|W_K|W_V -> wqkvT bf16 [2304][768] ;
//            W_O -> woT bf16 [768][768]^T
//   k_gemm<64,128,true>:  Q,K cols -> qkvb bf16 [4096][2304] (Q pre-scaled
//            0.125*log2e); V cols -> vtb [24][64][2048] DIRECTLY TRANSPOSED
//            (ushort4 over the e-axis = 4 consecutive s rows).  BM=64 ->
//            1152 blocks (4.5/CU co-resident).
//   k_flash: R13 verified: shared-prefix pairs (A: qiA=32+p, B: qiB=31-p),
//            768 uniform blocks, fixed-max softmax, swapped-operand MFMA.
//   k_gemm<64,64,false>:  d_out fp32 = zb @ woT^T + b_O
//
// ws: xb/zb @0 (6291456) | qkvb @6291456 (18874368) | vtb @25165824 (6291456)
//     wqkvT @31457280 (3538944) | woT @34996224 (1179648)   total 36175872 B

#define DEVINL __device__ __forceinline__

using bf16x8 = __attribute__((ext_vector_type(8))) __bf16;
using f32x4  = __attribute__((ext_vector_type(4))) float;

DEVINL unsigned short f32_bf16(float f) {
    unsigned u = __builtin_bit_cast(unsigned, f);
    return (unsigned short)((u + 0x7FFFu + ((u >> 16) & 1u)) >> 16);
}

DEVINL void gload16(const void* g, void* l) {
    __builtin_amdgcn_global_load_lds(
        (const __attribute__((address_space(1))) void*)g,
        (__attribute__((address_space(3))) void*)l, 16, 0, 0);
}

// ---------------- fused prep: convert + weight transposes ----------------
__global__ __launch_bounds__(256) void k_prep(const float* __restrict__ x,
                                              const float* __restrict__ Wq,
                                              const float* __restrict__ Wk,
                                              const float* __restrict__ Wv,
                                              const float* __restrict__ Wo,
                                              unsigned short* __restrict__ xb,
                                              unsigned short* __restrict__ wqkvT,
                                              unsigned short* __restrict__ woT) {
    __shared__ unsigned short tl[64][68];
    const int bid = blockIdx.x;
    const int t = threadIdx.x;
    if (bid < 3072) {
        int i = (bid * 256 + t) * 4;
        float4 v = *(const float4*)(x + i);
        ushort4 o;
        o.x = f32_bf16(v.x); o.y = f32_bf16(v.y); o.z = f32_bf16(v.z); o.w = f32_bf16(v.w);
        *(ushort4*)(xb + i) = o;
        return;
    }
    const int c = t & 63, r0 = t >> 6;
    if (bid < 3504) {
        const int sub = bid - 3072;          // 0..431
        const int tr = sub % 12, batch = sub / 12;   // batch 0..35
        const float* src = (batch < 12) ? Wq : (batch < 24) ? Wk : Wv;
        src += (size_t)(batch % 12) * 768 * 64;
        unsigned short* out = wqkvT + (size_t)batch * 64 * 768;
#pragma unroll
        for (int k = 0; k < 16; ++k) {
            int r = k * 4 + r0;
            tl[r][c] = f32_bf16(src[(size_t)(tr * 64 + r) * 64 + c]);
        }
        __syncthreads();
#pragma unroll
        for (int k = 0; k < 16; ++k) {
            int r2 = k * 4 + r0;
            out[(size_t)r2 * 768 + tr * 64 + c] = tl[c][r2];
        }
    } else {
        const int sub = bid - 3504;          // 0..143
        const int tr = sub % 12, tc = sub / 12;
#pragma unroll
        for (int k = 0; k < 16; ++k) {
            int r = k * 4 + r0;
            tl[r][c] = f32_bf16(Wo[(size_t)(tr * 64 + r) * 768 + tc * 64 + c]);
        }
        __syncthreads();
#pragma unroll
        for (int k = 0; k < 16; ++k) {
            int r2 = k * 4 + r0;
            woT[(size_t)(tc * 64 + r2) * 768 + tr * 64 + c] = tl[c][r2];
        }
    }
}

// ---------------- GEMM: C[4096][N] = A[4096][768] @ BT[N][768] + bias ----------------
// 2-phase double-buffered global_load_lds staging, one barrier per K-step.
// QKV=true: Q,K cols -> outb (Q scaled); V cols (col>=1536) -> vtb transposed.
template <int BM, int BN, bool QKV>
__global__ __launch_bounds__(256) void k_gemm(const unsigned short* __restrict__ A,
                                              const unsigned short* __restrict__ BT,
                                              const float* __restrict__ b0,
                                              const float* __restrict__ b1,
                                              const float* __restrict__ b2,
                                              unsigned short* __restrict__ outb,
                                              unsigned short* __restrict__ vtb,
                                              float* __restrict__ outf) {
    constexpr int LDC = QKV ? 2304 : 768;
    constexpr int WM = BM / 2, WN = BN / 2, MR = WM / 16, NR = WN / 16;
    __shared__ alignas(16) unsigned short As[2][BM * 32];
    __shared__ alignas(16) unsigned short Bs[2][BN * 32];
    const int t = threadIdx.x;
    const int w = t >> 6, l = t & 63, lr = l & 15, lg = l >> 4;
    const int wr = (w >> 1) * WM, wc = (w & 1) * WN;
    const int m0 = blockIdx.y * BM;
    const int n0 = blockIdx.x * BN;

    auto stage = [&](int buf, int kt) {
        const int k0 = kt * 32;
#pragma unroll
        for (int i = 0; i < BM / 64; ++i) {
            const int s = i * 256 + t;
            gload16((const char*)A + ((size_t)(m0 + (s >> 2)) * 768 + k0) * 2 + (s & 3) * 16,
                    (char*)As[buf] + s * 16);
        }
#pragma unroll
        for (int i = 0; i < BN / 64; ++i) {
            const int s = i * 256 + t;
            gload16((const char*)BT + ((size_t)(n0 + (s >> 2)) * 768 + k0) * 2 + (s & 3) * 16,
                    (char*)Bs[buf] + s * 16);
        }
    };

    stage(0, 0);
    __syncthreads();

    f32x4 acc[MR][NR] = {};

    for (int kt = 0; kt < 24; ++kt) {
        const int cur = kt & 1;
        if (kt < 23) stage(cur ^ 1, kt + 1);

        bf16x8 af[MR], bfr[NR];
#pragma unroll
        for (int ri = 0; ri < MR; ++ri)
            af[ri] = *(const bf16x8*)&As[cur][(wr + ri * 16 + lr) * 32 + lg * 8];
#pragma unroll
        for (int cj = 0; cj < NR; ++cj)
            bfr[cj] = *(const bf16x8*)&Bs[cur][(wc + cj * 16 + lr) * 32 + lg * 8];
        __builtin_amdgcn_s_setprio(1);
#pragma unroll
        for (int ri = 0; ri < MR; ++ri)
#pragma unroll
            for (int cj = 0; cj < NR; ++cj)
                acc[ri][cj] = __builtin_amdgcn_mfma_f32_16x16x32_bf16(
                    af[ri], bfr[cj], acc[ri][cj], 0, 0, 0);
        __builtin_amdgcn_s_setprio(0);
        __syncthreads();
    }

#pragma unroll
    for (int cj = 0; cj < NR; ++cj) {
        const int col = n0 + wc + cj * 16 + lr;
        if (QKV && col >= 1536) {
            // ---- V columns: write transposed into vtb[(b*12+h)][d][s] ----
            const int vc = col - 1536;
            const float bv = b2[vc];
            const int hh = vc >> 6, dd = vc & 63;
#pragma unroll
            for (int ri = 0; ri < MR; ++ri) {
                const int row = m0 + wr + ri * 16 + lg * 4;   // 4 consecutive s rows
                const int bb = row >> 11, s = row & 2047;
                ushort4 pkv;
                pkv.x = f32_bf16(acc[ri][cj][0] + bv);
                pkv.y = f32_bf16(acc[ri][cj][1] + bv);
                pkv.z = f32_bf16(acc[ri][cj][2] + bv);
                pkv.w = f32_bf16(acc[ri][cj][3] + bv);
                *(ushort4*)(vtb + ((size_t)(bb * 12 + hh) * 64 + dd) * 2048 + s) = pkv;
            }
        } else {
            const float* bp = b0;
            int cc = col;
            if (QKV && col >= 768) { bp = b1; cc = col - 768; }
            const float bv = bp[cc];
            const float scl = (QKV && col < 768) ? 0.18033688011112042f : 1.0f;  // 0.125*log2e
#pragma unroll
            for (int ri = 0; ri < MR; ++ri)
#pragma unroll
                for (int e = 0; e < 4; ++e) {
                    const int row = m0 + wr + ri * 16 + lg * 4 + e;
                    const float v = (acc[ri][cj][e] + bv) * scl;
                    if (QKV) outb[(size_t)row * LDC + col] = f32_bf16(v);
                    else     outf[(size_t)row * LDC + col] = v;
                }
        }
    }
}

// ---------------- flash attention: shared-prefix paired items (R13, verified) ---------
// grid (hb=24, p=32), 256 thr.  Item A: qiA=32+p; item B: qiB=31-p (same b,h).
// nkvA in [17,32], nkvB = 33-nkvA.  B's KV range is a prefix of A's.
#define WREG 8704
__global__ __launch_bounds__(256) void k_flash(const unsigned short* __restrict__ qkv,
                                               const unsigned short* __restrict__ vtb,
                                               unsigned short* __restrict__ zb) {
    __shared__ alignas(16) char smem[4 * WREG + 1024];
    const int hb = blockIdx.x;              // 0..23
    const int h = hb % 12, b = hb / 12;
    const int p = blockIdx.y;               // 0..31
    const int qiA = 32 + p, qiB = 31 - p;
    const int q0A = qiA * 32, q0B = qiB * 32;
    const int nkvA = (qiA >> 1) + 1, nkvB = (qiB >> 1) + 1;
    const int t = threadIdx.x, w = t >> 6, l = t & 63, lr = l & 15, lg = l >> 4;

    char* p_w = smem + w * WREG;                       // P[q][kv] bf16, swizzled
    float* lldsA = (float*)(smem + 4 * WREG);          // [4][32]
    float* lldsB = (float*)(smem + 4 * WREG + 512);    // [4][32]

    const size_t qrowbase = (size_t)(b * 2048) * 2304;
    bf16x8 qfA[2][2], qfB[2][2];
#pragma unroll
    for (int ri = 0; ri < 2; ++ri)
#pragma unroll
        for (int kk = 0; kk < 2; ++kk) {
            qfA[ri][kk] = *(const bf16x8*)(qkv + qrowbase +
                                           (size_t)(q0A + ri * 16 + lr) * 2304 +
                                           h * 64 + kk * 32 + lg * 8);
            qfB[ri][kk] = *(const bf16x8*)(qkv + qrowbase +
                                           (size_t)(q0B + ri * 16 + lr) * 2304 +
                                           h * 64 + kk * 32 + lg * 8);
        }

    f32x4 oA[2][4] = {}, oB[2][4] = {};
    float lsA[2] = {0.f, 0.f}, lsB[2] = {0.f, 0.f};

    const unsigned short* kb = qkv + qrowbase + 768 + h * 64;     // K cols
    const unsigned short* vt = vtb + (size_t)(b * 12 + h) * 64 * 2048;

    {
        bf16x8 kf[4][2];
        auto loadK = [&](int kv0) {
#pragma unroll
            for (int cj = 0; cj < 4; ++cj)
#pragma unroll
                for (int kk = 0; kk < 2; ++kk)
                    kf[cj][kk] = *(const bf16x8*)(kb + (size_t)(kv0 + cj * 16 + lr) * 2304 +
                                                  kk * 32 + lg * 8);
        };

        int kt = w;                // nkvA >= 17 > 4, so every wave has work
        loadK(kt * 64);
        do {
            const int kv0 = kt * 64;

            // V fragments issued FIRST -> latency covered by B+A compute
            bf16x8 vf[2][4];
#pragma unroll
            for (int kk = 0; kk < 2; ++kk)
#pragma unroll
                for (int dj = 0; dj < 4; ++dj)
                    vf[kk][dj] = *(const bf16x8*)(vt + (size_t)(dj * 16 + lr) * 2048 +
                                                  kv0 + kk * 32 + lg * 8);

            const f32x4 zz = {0.f, 0.f, 0.f, 0.f};

            // ================= item B (prefix rider) =================
            if (kt < nkvB) {
                f32x4 st[2][4];
                __builtin_amdgcn_s_setprio(1);
#pragma unroll
                for (int ri = 0; ri < 2; ++ri)
#pragma unroll
                    for (int cj = 0; cj < 4; ++cj) {
                        f32x4 a0 = __builtin_amdgcn_mfma_f32_16x16x32_bf16(kf[cj][0], qfB[ri][0], zz, 0, 0, 0);
                        st[ri][cj] = __builtin_amdgcn_mfma_f32_16x16x32_bf16(kf[cj][1], qfB[ri][1], a0, 0, 0, 0);
                    }
                __builtin_amdgcn_s_setprio(0);

                if (kt == nkvB - 1) {
#pragma unroll
                    for (int ri = 0; ri < 2; ++ri)
#pragma unroll
                        for (int cj = 0; cj < 4; ++cj)
#pragma unroll
                            for (int e = 0; e < 4; ++e) {
                                const int kvv = kv0 + cj * 16 + lg * 4 + e;
                                const int qq  = q0B + ri * 16 + lr;
                                if (kvv > qq) st[ri][cj][e] = -1e30f;
                            }
                }

#pragma unroll
                for (int ri = 0; ri < 2; ++ri) {
                    float ps = 0.f;
#pragma unroll
                    for (int cj = 0; cj < 4; ++cj)
#pragma unroll
                        for (int e = 0; e < 4; ++e) {
                            const float pv = __builtin_amdgcn_exp2f(st[ri][cj][e]);
                            st[ri][cj][e] = pv;
                            ps += pv;
                        }
                    lsB[ri] += ps;

                    const int row = ri * 16 + lr;
#pragma unroll
                    for (int cj = 0; cj < 4; ++cj) {
                        unsigned lo, hi;
                        asm("v_cvt_pk_bf16_f32 %0, %1, %2"
                            : "=v"(lo) : "v"(st[ri][cj][0]), "v"(st[ri][cj][1]));
                        asm("v_cvt_pk_bf16_f32 %0, %1, %2"
                            : "=v"(hi) : "v"(st[ri][cj][2]), "v"(st[ri][cj][3]));
                        const int gr = (cj * 2 + (lg >> 1)) ^ (lr & 7);
                        uint2 pk2; pk2.x = lo; pk2.y = hi;
                        *(uint2*)(p_w + row * 128 + gr * 16 + (lg & 1) * 8) = pk2;
                    }
                }

                asm volatile("" ::: "memory");

                __builtin_amdgcn_s_setprio(1);
#pragma unroll
                for (int kk = 0; kk < 2; ++kk)
#pragma unroll
                    for (int ri = 0; ri < 2; ++ri) {
                        const int row = ri * 16 + lr;
                        const int g = (kk * 4 + lg) ^ (lr & 7);
                        bf16x8 pa = *(const bf16x8*)(p_w + row * 128 + g * 16);
#pragma unroll
                        for (int dj = 0; dj < 4; ++dj)
                            oB[ri][dj] = __builtin_amdgcn_mfma_f32_16x16x32_bf16(
                                vf[kk][dj], pa, oB[ri][dj], 0, 0, 0);
                    }
                __builtin_amdgcn_s_setprio(0);

                asm volatile("" ::: "memory");
            }

            // ================= item A =================
            {
                f32x4 st[2][4];
                __builtin_amdgcn_s_setprio(1);
#pragma unroll
                for (int ri = 0; ri < 2; ++ri)
#pragma unroll
                    for (int cj = 0; cj < 4; ++cj) {
                        f32x4 a0 = __builtin_amdgcn_mfma_f32_16x16x32_bf16(kf[cj][0], qfA[ri][0], zz, 0, 0, 0);
                        st[ri][cj] = __builtin_amdgcn_mfma_f32_16x16x32_bf16(kf[cj][1], qfA[ri][1], a0, 0, 0, 0);
                    }
                __builtin_amdgcn_s_setprio(0);

                if (kt == nkvA - 1) {
#pragma unroll
                    for (int ri = 0; ri < 2; ++ri)
#pragma unroll
                        for (int cj = 0; cj < 4; ++cj)
#pragma unroll
                            for (int e = 0; e < 4; ++e) {
                                const int kvv = kv0 + cj * 16 + lg * 4 + e;
                                const int qq  = q0A + ri * 16 + lr;
                                if (kvv > qq) st[ri][cj][e] = -1e30f;
                            }
                }

#pragma unroll
                for (int ri = 0; ri < 2; ++ri) {
                    float ps = 0.f;
#pragma unroll
                    for (int cj = 0; cj < 4; ++cj)
#pragma unroll
                        for (int e = 0; e < 4; ++e) {
                            const float pv = __builtin_amdgcn_exp2f(st[ri][cj][e]);
                            st[ri][cj][e] = pv;
                            ps += pv;
                        }
                    lsA[ri] += ps;

                    const int row = ri * 16 + lr;
#pragma unroll
                    for (int cj = 0; cj < 4; ++cj) {
                        unsigned lo, hi;
                        asm("v_cvt_pk_bf16_f32 %0, %1, %2"
                            : "=v"(lo) : "v"(st[ri][cj][0]), "v"(st[ri][cj][1]));
                        asm("v_cvt_pk_bf16_f32 %0, %1, %2"
                            : "=v"(hi) : "v"(st[ri][cj][2]), "v"(st[ri][cj][3]));
                        const int gr = (cj * 2 + (lg >> 1)) ^ (lr & 7);
                        uint2 pk2; pk2.x = lo; pk2.y = hi;
                        *(uint2*)(p_w + row * 128 + gr * 16 + (lg & 1) * 8) = pk2;
                    }
                }

                asm volatile("" ::: "memory");

                // prefetch next K tile (kf dead after A-QK) under A's PV
                const bool more = (kt + 4 < nkvA);
                if (more) loadK(kv0 + 256);

                __builtin_amdgcn_s_setprio(1);
#pragma unroll
                for (int kk = 0; kk < 2; ++kk)
#pragma unroll
                    for (int ri = 0; ri < 2; ++ri) {
                        const int row = ri * 16 + lr;
                        const int g = (kk * 4 + lg) ^ (lr & 7);
                        bf16x8 pa = *(const bf16x8*)(p_w + row * 128 + g * 16);
#pragma unroll
                        for (int dj = 0; dj < 4; ++dj)
                            oA[ri][dj] = __builtin_amdgcn_mfma_f32_16x16x32_bf16(
                                vf[kk][dj], pa, oA[ri][dj], 0, 0, 0);
                    }
                __builtin_amdgcn_s_setprio(0);

                asm volatile("" ::: "memory");
            }

            kt += 4;
        } while (kt < nkvA);
    }

    // ---- row-total denominators for both items ----
#pragma unroll
    for (int ri = 0; ri < 2; ++ri) {
        float a = lsA[ri];
        a += __shfl_xor(a, 16); a += __shfl_xor(a, 32);
        lsA[ri] = a;
        float bsum = lsB[ri];
        bsum += __shfl_xor(bsum, 16); bsum += __shfl_xor(bsum, 32);
        lsB[ri] = bsum;
    }
    if (lg == 0) {
#pragma unroll
        for (int ri = 0; ri < 2; ++ri) {
            lldsA[w * 32 + ri * 16 + lr] = lsA[ri];
            lldsB[w * 32 + ri * 16 + lr] = lsB[ri];
        }
    }
    __syncthreads();   // loops done; P regions dead; llds complete

    // ---- merge item A, then item B (reusing scratch) ----
#pragma unroll
    for (int item = 0; item < 2; ++item) {
        const float* lld = item ? lldsB : lldsA;
        const int q0 = item ? q0B : q0A;
        float* o_w = (float*)(smem + w * WREG);  // [32][68] f32
#pragma unroll
        for (int ri = 0; ri < 2; ++ri) {
            const int row = ri * 16 + lr;
#pragma unroll
            for (int dj = 0; dj < 4; ++dj)
                *(f32x4*)&o_w[row * 68 + dj * 16 + lg * 4] = item ? oB[ri][dj] : oA[ri][dj];
        }
        __syncthreads();
        {
            const int row = w * 8 + (l >> 3);
            const int c0 = (l & 7) * 8;
            const float lt = lld[row] + lld[32 + row] + lld[64 + row] + lld[96 + row];
            const float inv = 1.0f / lt;
            ushort4 pk[2];
#pragma unroll
            for (int half = 0; half < 2; ++half) {
                unsigned short u[4];
#pragma unroll
                for (int k = 0; k < 4; ++k) {
                    float acc = 0.f;
#pragma unroll
                    for (int s = 0; s < 4; ++s)
                        acc += ((const float*)(smem + s * WREG))[row * 68 + c0 + half * 4 + k];
                    u[k] = f32_bf16(acc * inv);
                }
                pk[half] = make_ushort4(u[0], u[1], u[2], u[3]);
            }
            unsigned short* dst = zb + (size_t)(b * 2048 + q0 + row) * 768 + h * 64 + c0;
            *(ushort4*)dst = pk[0];
            *(ushort4*)(dst + 4) = pk[1];
        }
        __syncthreads();
    }
}

extern "C" void kernel_launch(void* const* d_in, const int* in_sizes, int n_in,
                              void* d_out, int out_size, void* d_ws, size_t ws_size,
                              hipStream_t stream) {
    (void)in_sizes; (void)n_in; (void)out_size; (void)ws_size;
    const float* x   = (const float*)d_in[0];
    const float* W_Q = (const float*)d_in[1];
    const float* W_K = (const float*)d_in[2];
    const float* W_V = (const float*)d_in[3];
    const float* b_Q = (const float*)d_in[4];
    const float* b_K = (const float*)d_in[5];
    const float* b_V = (const float*)d_in[6];
    const float* W_O = (const float*)d_in[7];
    const float* b_O = (const float*)d_in[8];
    float* out = (float*)d_out;

    char* ws = (char*)d_ws;
    unsigned short* xb    = (unsigned short*)(ws);
    unsigned short* qkvb  = (unsigned short*)(ws + 6291456);
    unsigned short* vtb   = (unsigned short*)(ws + 25165824);
    unsigned short* wqkvT = (unsigned short*)(ws + 31457280);
    unsigned short* woT   = (unsigned short*)(ws + 34996224);
    unsigned short* zb    = xb;  // xb dead after the QKV GEMM

    k_prep<<<3648, 256, 0, stream>>>(x, W_Q, W_K, W_V, W_O, xb, wqkvT, woT);

    k_gemm<64, 128, true><<<dim3(18, 64), 256, 0, stream>>>(xb, wqkvT, b_Q, b_K, b_V,
                                                            qkvb, vtb, nullptr);

    k_flash<<<dim3(24, 32), 256, 0, stream>>>(qkvb, vtb, zb);

    k_gemm<64, 64, false><<<dim3(12, 64), 256, 0, stream>>>(zb, woT, b_O, b_O, b_O,
                                                            nullptr, nullptr, out);
}

// Round 16
// 95.585 us; speedup vs baseline: 1.3095x; 1.1413x over previous
//
#include <hip/hip_runtime.h>

// Fused causal MHA on gfx950.  Pipeline (R15 = R14 + BK=64 swizzled GEMMs):
//   k_prep:  x fp32 -> xb bf16 ; W_Q|W_K|W_V -> wqkvT bf16 [2304][768] ;
//            W_O -> woT bf16 [768][768]^T
//   k_gemm<128,64,true>:  Q,K cols -> qkvb bf16 [4096][2304] (Q pre-scaled
//            0.125*log2e); V cols -> vtb [24][64][2048] transposed.
//            BK=64: 12 barriers (was 24).  LDS dest linear (gload_lds), global
//            source chunk-XOR-swizzled; reads use same involution -> ~2-way
//            bank conflicts (free) instead of 16-way.
//   k_flash: R13 verified: shared-prefix pairs (A: qiA=32+p, B: qiB=31-p),
//            768 uniform blocks, fixed-max softmax, swapped-operand MFMA.
//   k_gemm<64,64,false>:  d_out fp32 = zb @ woT^T + b_O  (BK=64 swizzled too)
//
// ws: xb/zb @0 (6291456) | qkvb @6291456 (18874368) | vtb @25165824 (6291456)
//     wqkvT @31457280 (3538944) | woT @34996224 (1179648)   total 36175872 B

#define DEVINL __device__ __forceinline__

using bf16x8 = __attribute__((ext_vector_type(8))) __bf16;
using f32x4  = __attribute__((ext_vector_type(4))) float;

DEVINL unsigned short f32_bf16(float f) {
    unsigned u = __builtin_bit_cast(unsigned, f);
    return (unsigned short)((u + 0x7FFFu + ((u >> 16) & 1u)) >> 16);
}

DEVINL void gload16(const void* g, void* l) {
    __builtin_amdgcn_global_load_lds(
        (const __attribute__((address_space(1))) void*)g,
        (__attribute__((address_space(3))) void*)l, 16, 0, 0);
}

// ---------------- fused prep: convert + weight transposes ----------------
__global__ __launch_bounds__(256) void k_prep(const float* __restrict__ x,
                                              const float* __restrict__ Wq,
                                              const float* __restrict__ Wk,
                                              const float* __restrict__ Wv,
                                              const float* __restrict__ Wo,
                                              unsigned short* __restrict__ xb,
                                              unsigned short* __restrict__ wqkvT,
                                              unsigned short* __restrict__ woT) {
    __shared__ unsigned short tl[64][68];
    const int bid = blockIdx.x;
    const int t = threadIdx.x;
    if (bid < 3072) {
        int i = (bid * 256 + t) * 4;
        float4 v = *(const float4*)(x + i);
        ushort4 o;
        o.x = f32_bf16(v.x); o.y = f32_bf16(v.y); o.z = f32_bf16(v.z); o.w = f32_bf16(v.w);
        *(ushort4*)(xb + i) = o;
        return;
    }
    const int c = t & 63, r0 = t >> 6;
    if (bid < 3504) {
        const int sub = bid - 3072;          // 0..431
        const int tr = sub % 12, batch = sub / 12;   // batch 0..35
        const float* src = (batch < 12) ? Wq : (batch < 24) ? Wk : Wv;
        src += (size_t)(batch % 12) * 768 * 64;
        unsigned short* out = wqkvT + (size_t)batch * 64 * 768;
#pragma unroll
        for (int k = 0; k < 16; ++k) {
            int r = k * 4 + r0;
            tl[r][c] = f32_bf16(src[(size_t)(tr * 64 + r) * 64 + c]);
        }
        __syncthreads();
#pragma unroll
        for (int k = 0; k < 16; ++k) {
            int r2 = k * 4 + r0;
            out[(size_t)r2 * 768 + tr * 64 + c] = tl[c][r2];
        }
    } else {
        const int sub = bid - 3504;          // 0..143
        const int tr = sub % 12, tc = sub / 12;
#pragma unroll
        for (int k = 0; k < 16; ++k) {
            int r = k * 4 + r0;
            tl[r][c] = f32_bf16(Wo[(size_t)(tr * 64 + r) * 768 + tc * 64 + c]);
        }
        __syncthreads();
#pragma unroll
        for (int k = 0; k < 16; ++k) {
            int r2 = k * 4 + r0;
            woT[(size_t)(tc * 64 + r2) * 768 + tr * 64 + c] = tl[c][r2];
        }
    }
}

// ---------------- GEMM: C[4096][N] = A[4096][768] @ BT[N][768] + bias ----------------
// BK=64, 2-phase dbuf, one barrier/K-step (12 steps).  LDS rows are 64 bf16
// (128 B) split into 8 16B chunks; global source chunk index is XOR-swizzled
// (cs = (s&7)^(row&7)) so the linear-LDS gload_lds ends up bank-spread; the
// fragment reads apply the same involution -> ~2-way conflicts (free).
// QKV=true: Q,K cols -> outb (Q scaled); V cols (col>=1536) -> vtb transposed.
template <int BM, int BN, bool QKV>
__global__ __launch_bounds__(256) void k_gemm(const unsigned short* __restrict__ A,
                                              const unsigned short* __restrict__ BT,
                                              const float* __restrict__ b0,
                                              const float* __restrict__ b1,
                                              const float* __restrict__ b2,
                                              unsigned short* __restrict__ outb,
                                              unsigned short* __restrict__ vtb,
                                              float* __restrict__ outf) {
    constexpr int LDC = QKV ? 2304 : 768;
    constexpr int WM = BM / 2, WN = BN / 2, MR = WM / 16, NR = WN / 16;
    __shared__ alignas(16) unsigned short As[2][BM * 64];
    __shared__ alignas(16) unsigned short Bs[2][BN * 64];
    const int t = threadIdx.x;
    const int w = t >> 6, l = t & 63, lr = l & 15, lg = l >> 4;
    const int wr = (w >> 1) * WM, wc = (w & 1) * WN;
    const int m0 = blockIdx.y * BM;
    const int n0 = blockIdx.x * BN;

    auto stage = [&](int buf, int kt) {
        const int k0 = kt * 64;
#pragma unroll
        for (int i = 0; i < BM / 32; ++i) {
            const int s = i * 256 + t;
            const int row = s >> 3, cs = (s & 7) ^ (row & 7);
            gload16((const char*)A + ((size_t)(m0 + row) * 768 + k0) * 2 + cs * 16,
                    (char*)As[buf] + s * 16);
        }
#pragma unroll
        for (int i = 0; i < BN / 32; ++i) {
            const int s = i * 256 + t;
            const int row = s >> 3, cs = (s & 7) ^ (row & 7);
            gload16((const char*)BT + ((size_t)(n0 + row) * 768 + k0) * 2 + cs * 16,
                    (char*)Bs[buf] + s * 16);
        }
    };

    stage(0, 0);
    __syncthreads();

    f32x4 acc[MR][NR] = {};

    for (int kt = 0; kt < 12; ++kt) {
        const int cur = kt & 1;
        if (kt < 11) stage(cur ^ 1, kt + 1);

        bf16x8 af[MR][2], bfr[NR][2];
#pragma unroll
        for (int ri = 0; ri < MR; ++ri)
#pragma unroll
            for (int kk = 0; kk < 2; ++kk)
                af[ri][kk] = *(const bf16x8*)&As[cur][(wr + ri * 16 + lr) * 64 +
                                                     (((kk * 4 + lg) ^ (lr & 7)) << 3)];
#pragma unroll
        for (int cj = 0; cj < NR; ++cj)
#pragma unroll
            for (int kk = 0; kk < 2; ++kk)
                bfr[cj][kk] = *(const bf16x8*)&Bs[cur][(wc + cj * 16 + lr) * 64 +
                                                       (((kk * 4 + lg) ^ (lr & 7)) << 3)];
        __builtin_amdgcn_s_setprio(1);
#pragma unroll
        for (int ri = 0; ri < MR; ++ri)
#pragma unroll
            for (int cj = 0; cj < NR; ++cj) {
                acc[ri][cj] = __builtin_amdgcn_mfma_f32_16x16x32_bf16(
                    af[ri][0], bfr[cj][0], acc[ri][cj], 0, 0, 0);
                acc[ri][cj] = __builtin_amdgcn_mfma_f32_16x16x32_bf16(
                    af[ri][1], bfr[cj][1], acc[ri][cj], 0, 0, 0);
            }
        __builtin_amdgcn_s_setprio(0);
        __syncthreads();
    }

#pragma unroll
    for (int cj = 0; cj < NR; ++cj) {
        const int col = n0 + wc + cj * 16 + lr;
        if (QKV && col >= 1536) {
            // ---- V columns: write transposed into vtb[(b*12+h)][d][s] ----
            const int vc = col - 1536;
            const float bv = b2[vc];
            const int hh = vc >> 6, dd = vc & 63;
#pragma unroll
            for (int ri = 0; ri < MR; ++ri) {
                const int row = m0 + wr + ri * 16 + lg * 4;   // 4 consecutive s rows
                const int bb = row >> 11, s = row & 2047;
                ushort4 pkv;
                pkv.x = f32_bf16(acc[ri][cj][0] + bv);
                pkv.y = f32_bf16(acc[ri][cj][1] + bv);
                pkv.z = f32_bf16(acc[ri][cj][2] + bv);
                pkv.w = f32_bf16(acc[ri][cj][3] + bv);
                *(ushort4*)(vtb + ((size_t)(bb * 12 + hh) * 64 + dd) * 2048 + s) = pkv;
            }
        } else {
            const float* bp = b0;
            int cc = col;
            if (QKV && col >= 768) { bp = b1; cc = col - 768; }
            const float bv = bp[cc];
            const float scl = (QKV && col < 768) ? 0.18033688011112042f : 1.0f;  // 0.125*log2e
#pragma unroll
            for (int ri = 0; ri < MR; ++ri)
#pragma unroll
                for (int e = 0; e < 4; ++e) {
                    const int row = m0 + wr + ri * 16 + lg * 4 + e;
                    const float v = (acc[ri][cj][e] + bv) * scl;
                    if (QKV) outb[(size_t)row * LDC + col] = f32_bf16(v);
                    else     outf[(size_t)row * LDC + col] = v;
                }
        }
    }
}

// ---------------- flash attention: shared-prefix paired items (R13, verified) ---------
// grid (hb=24, p=32), 256 thr.  Item A: qiA=32+p; item B: qiB=31-p (same b,h).
// nkvA in [17,32], nkvB = 33-nkvA.  B's KV range is a prefix of A's.
#define WREG 8704
__global__ __launch_bounds__(256) void k_flash(const unsigned short* __restrict__ qkv,
                                               const unsigned short* __restrict__ vtb,
                                               unsigned short* __restrict__ zb) {
    __shared__ alignas(16) char smem[4 * WREG + 1024];
    const int hb = blockIdx.x;              // 0..23
    const int h = hb % 12, b = hb / 12;
    const int p = blockIdx.y;               // 0..31
    const int qiA = 32 + p, qiB = 31 - p;
    const int q0A = qiA * 32, q0B = qiB * 32;
    const int nkvA = (qiA >> 1) + 1, nkvB = (qiB >> 1) + 1;
    const int t = threadIdx.x, w = t >> 6, l = t & 63, lr = l & 15, lg = l >> 4;

    char* p_w = smem + w * WREG;                       // P[q][kv] bf16, swizzled
    float* lldsA = (float*)(smem + 4 * WREG);          // [4][32]
    float* lldsB = (float*)(smem + 4 * WREG + 512);    // [4][32]

    const size_t qrowbase = (size_t)(b * 2048) * 2304;
    bf16x8 qfA[2][2], qfB[2][2];
#pragma unroll
    for (int ri = 0; ri < 2; ++ri)
#pragma unroll
        for (int kk = 0; kk < 2; ++kk) {
            qfA[ri][kk] = *(const bf16x8*)(qkv + qrowbase +
                                           (size_t)(q0A + ri * 16 + lr) * 2304 +
                                           h * 64 + kk * 32 + lg * 8);
            qfB[ri][kk] = *(const bf16x8*)(qkv + qrowbase +
                                           (size_t)(q0B + ri * 16 + lr) * 2304 +
                                           h * 64 + kk * 32 + lg * 8);
        }

    f32x4 oA[2][4] = {}, oB[2][4] = {};
    float lsA[2] = {0.f, 0.f}, lsB[2] = {0.f, 0.f};

    const unsigned short* kb = qkv + qrowbase + 768 + h * 64;     // K cols
    const unsigned short* vt = vtb + (size_t)(b * 12 + h) * 64 * 2048;

    {
        bf16x8 kf[4][2];
        auto loadK = [&](int kv0) {
#pragma unroll
            for (int cj = 0; cj < 4; ++cj)
#pragma unroll
                for (int kk = 0; kk < 2; ++kk)
                    kf[cj][kk] = *(const bf16x8*)(kb + (size_t)(kv0 + cj * 16 + lr) * 2304 +
                                                  kk * 32 + lg * 8);
        };

        int kt = w;                // nkvA >= 17 > 4, so every wave has work
        loadK(kt * 64);
        do {
            const int kv0 = kt * 64;

            // V fragments issued FIRST -> latency covered by B+A compute
            bf16x8 vf[2][4];
#pragma unroll
            for (int kk = 0; kk < 2; ++kk)
#pragma unroll
                for (int dj = 0; dj < 4; ++dj)
                    vf[kk][dj] = *(const bf16x8*)(vt + (size_t)(dj * 16 + lr) * 2048 +
                                                  kv0 + kk * 32 + lg * 8);

            const f32x4 zz = {0.f, 0.f, 0.f, 0.f};

            // ================= item B (prefix rider) =================
            if (kt < nkvB) {
                f32x4 st[2][4];
                __builtin_amdgcn_s_setprio(1);
#pragma unroll
                for (int ri = 0; ri < 2; ++ri)
#pragma unroll
                    for (int cj = 0; cj < 4; ++cj) {
                        f32x4 a0 = __builtin_amdgcn_mfma_f32_16x16x32_bf16(kf[cj][0], qfB[ri][0], zz, 0, 0, 0);
                        st[ri][cj] = __builtin_amdgcn_mfma_f32_16x16x32_bf16(kf[cj][1], qfB[ri][1], a0, 0, 0, 0);
                    }
                __builtin_amdgcn_s_setprio(0);

                if (kt == nkvB - 1) {
#pragma unroll
                    for (int ri = 0; ri < 2; ++ri)
#pragma unroll
                        for (int cj = 0; cj < 4; ++cj)
#pragma unroll
                            for (int e = 0; e < 4; ++e) {
                                const int kvv = kv0 + cj * 16 + lg * 4 + e;
                                const int qq  = q0B + ri * 16 + lr;
                                if (kvv > qq) st[ri][cj][e] = -1e30f;
                            }
                }

#pragma unroll
                for (int ri = 0; ri < 2; ++ri) {
                    float ps = 0.f;
#pragma unroll
                    for (int cj = 0; cj < 4; ++cj)
#pragma unroll
                        for (int e = 0; e < 4; ++e) {
                            const float pv = __builtin_amdgcn_exp2f(st[ri][cj][e]);
                            st[ri][cj][e] = pv;
                            ps += pv;
                        }
                    lsB[ri] += ps;

                    const int row = ri * 16 + lr;
#pragma unroll
                    for (int cj = 0; cj < 4; ++cj) {
                        unsigned lo, hi;
                        asm("v_cvt_pk_bf16_f32 %0, %1, %2"
                            : "=v"(lo) : "v"(st[ri][cj][0]), "v"(st[ri][cj][1]));
                        asm("v_cvt_pk_bf16_f32 %0, %1, %2"
                            : "=v"(hi) : "v"(st[ri][cj][2]), "v"(st[ri][cj][3]));
                        const int gr = (cj * 2 + (lg >> 1)) ^ (lr & 7);
                        uint2 pk2; pk2.x = lo; pk2.y = hi;
                        *(uint2*)(p_w + row * 128 + gr * 16 + (lg & 1) * 8) = pk2;
                    }
                }

                asm volatile("" ::: "memory");

                __builtin_amdgcn_s_setprio(1);
#pragma unroll
                for (int kk = 0; kk < 2; ++kk)
#pragma unroll
                    for (int ri = 0; ri < 2; ++ri) {
                        const int row = ri * 16 + lr;
                        const int g = (kk * 4 + lg) ^ (lr & 7);
                        bf16x8 pa = *(const bf16x8*)(p_w + row * 128 + g * 16);
#pragma unroll
                        for (int dj = 0; dj < 4; ++dj)
                            oB[ri][dj] = __builtin_amdgcn_mfma_f32_16x16x32_bf16(
                                vf[kk][dj], pa, oB[ri][dj], 0, 0, 0);
                    }
                __builtin_amdgcn_s_setprio(0);

                asm volatile("" ::: "memory");
            }

            // ================= item A =================
            {
                f32x4 st[2][4];
                __builtin_amdgcn_s_setprio(1);
#pragma unroll
                for (int ri = 0; ri < 2; ++ri)
#pragma unroll
                    for (int cj = 0; cj < 4; ++cj) {
                        f32x4 a0 = __builtin_amdgcn_mfma_f32_16x16x32_bf16(kf[cj][0], qfA[ri][0], zz, 0, 0, 0);
                        st[ri][cj] = __builtin_amdgcn_mfma_f32_16x16x32_bf16(kf[cj][1], qfA[ri][1], a0, 0, 0, 0);
                    }
                __builtin_amdgcn_s_setprio(0);

                if (kt == nkvA - 1) {
#pragma unroll
                    for (int ri = 0; ri < 2; ++ri)
#pragma unroll
                        for (int cj = 0; cj < 4; ++cj)
#pragma unroll
                            for (int e = 0; e < 4; ++e) {
                                const int kvv = kv0 + cj * 16 + lg * 4 + e;
                                const int qq  = q0A + ri * 16 + lr;
                                if (kvv > qq) st[ri][cj][e] = -1e30f;
                            }
                }

#pragma unroll
                for (int ri = 0; ri < 2; ++ri) {
                    float ps = 0.f;
#pragma unroll
                    for (int cj = 0; cj < 4; ++cj)
#pragma unroll
                        for (int e = 0; e < 4; ++e) {
                            const float pv = __builtin_amdgcn_exp2f(st[ri][cj][e]);
                            st[ri][cj][e] = pv;
                            ps += pv;
                        }
                    lsA[ri] += ps;

                    const int row = ri * 16 + lr;
#pragma unroll
                    for (int cj = 0; cj < 4; ++cj) {
                        unsigned lo, hi;
                        asm("v_cvt_pk_bf16_f32 %0, %1, %2"
                            : "=v"(lo) : "v"(st[ri][cj][0]), "v"(st[ri][cj][1]));
                        asm("v_cvt_pk_bf16_f32 %0, %1, %2"
                            : "=v"(hi) : "v"(st[ri][cj][2]), "v"(st[ri][cj][3]));
                        const int gr = (cj * 2 + (lg >> 1)) ^ (lr & 7);
                        uint2 pk2; pk2.x = lo; pk2.y = hi;
                        *(uint2*)(p_w + row * 128 + gr * 16 + (lg & 1) * 8) = pk2;
                    }
                }

                asm volatile("" ::: "memory");

                // prefetch next K tile (kf dead after A-QK) under A's PV
                const bool more = (kt + 4 < nkvA);
                if (more) loadK(kv0 + 256);

                __builtin_amdgcn_s_setprio(1);
#pragma unroll
                for (int kk = 0; kk < 2; ++kk)
#pragma unroll
                    for (int ri = 0; ri < 2; ++ri) {
                        const int row = ri * 16 + lr;
                        const int g = (kk * 4 + lg) ^ (lr & 7);
                        bf16x8 pa = *(const bf16x8*)(p_w + row * 128 + g * 16);
#pragma unroll
                        for (int dj = 0; dj < 4; ++dj)
                            oA[ri][dj] = __builtin_amdgcn_mfma_f32_16x16x32_bf16(
                                vf[kk][dj], pa, oA[ri][dj], 0, 0, 0);
                    }
                __builtin_amdgcn_s_setprio(0);

                asm volatile("" ::: "memory");
            }

            kt += 4;
        } while (kt < nkvA);
    }

    // ---- row-total denominators for both items ----
#pragma unroll
    for (int ri = 0; ri < 2; ++ri) {
        float a = lsA[ri];
        a += __shfl_xor(a, 16); a += __shfl_xor(a, 32);
        lsA[ri] = a;
        float bsum = lsB[ri];
        bsum += __shfl_xor(bsum, 16); bsum += __shfl_xor(bsum, 32);
        lsB[ri] = bsum;
    }
    if (lg == 0) {
#pragma unroll
        for (int ri = 0; ri < 2; ++ri) {
            lldsA[w * 32 + ri * 16 + lr] = lsA[ri];
            lldsB[w * 32 + ri * 16 + lr] = lsB[ri];
        }
    }
    __syncthreads();   // loops done; P regions dead; llds complete

    // ---- merge item A, then item B (reusing scratch) ----
#pragma unroll
    for (int item = 0; item < 2; ++item) {
        const float* lld = item ? lldsB : lldsA;
        const int q0 = item ? q0B : q0A;
        float* o_w = (float*)(smem + w * WREG);  // [32][68] f32
#pragma unroll
        for (int ri = 0; ri < 2; ++ri) {
            const int row = ri * 16 + lr;
#pragma unroll
            for (int dj = 0; dj < 4; ++dj)
                *(f32x4*)&o_w[row * 68 + dj * 16 + lg * 4] = item ? oB[ri][dj] : oA[ri][dj];
        }
        __syncthreads();
        {
            const int row = w * 8 + (l >> 3);
            const int c0 = (l & 7) * 8;
            const float lt = lld[row] + lld[32 + row] + lld[64 + row] + lld[96 + row];
            const float inv = 1.0f / lt;
            ushort4 pk[2];
#pragma unroll
            for (int half = 0; half < 2; ++half) {
                unsigned short u[4];
#pragma unroll
                for (int k = 0; k < 4; ++k) {
                    float acc = 0.f;
#pragma unroll
                    for (int s = 0; s < 4; ++s)
                        acc += ((const float*)(smem + s * WREG))[row * 68 + c0 + half * 4 + k];
                    u[k] = f32_bf16(acc * inv);
                }
                pk[half] = make_ushort4(u[0], u[1], u[2], u[3]);
            }
            unsigned short* dst = zb + (size_t)(b * 2048 + q0 + row) * 768 + h * 64 + c0;
            *(ushort4*)dst = pk[0];
            *(ushort4*)(dst + 4) = pk[1];
        }
        __syncthreads();
    }
}

extern "C" void kernel_launch(void* const* d_in, const int* in_sizes, int n_in,
                              void* d_out, int out_size, void* d_ws, size_t ws_size,
                              hipStream_t stream) {
    (void)in_sizes; (void)n_in; (void)out_size; (void)ws_size;
    const float* x   = (const float*)d_in[0];
    const float* W_Q = (const float*)d_in[1];
    const float* W_K = (const float*)d_in[2];
    const float* W_V = (const float*)d_in[3];
    const float* b_Q = (const float*)d_in[4];
    const float* b_K = (const float*)d_in[5];
    const float* b_V = (const float*)d_in[6];
    const float* W_O = (const float*)d_in[7];
    const float* b_O = (const float*)d_in[8];
    float* out = (float*)d_out;

    char* ws = (char*)d_ws;
    unsigned short* xb    = (unsigned short*)(ws);
    unsigned short* qkvb  = (unsigned short*)(ws + 6291456);
    unsigned short* vtb   = (unsigned short*)(ws + 25165824);
    unsigned short* wqkvT = (unsigned short*)(ws + 31457280);
    unsigned short* woT   = (unsigned short*)(ws + 34996224);
    unsigned short* zb    = xb;  // xb dead after the QKV GEMM

    k_prep<<<3648, 256, 0, stream>>>(x, W_Q, W_K, W_V, W_O, xb, wqkvT, woT);

    k_gemm<128, 64, true><<<dim3(36, 32), 256, 0, stream>>>(xb, wqkvT, b_Q, b_K, b_V,
                                                            qkvb, vtb, nullptr);

    k_flash<<<dim3(24, 32), 256, 0, stream>>>(qkvb, vtb, zb);

    k_gemm<64, 64, false><<<dim3(12, 64), 256, 0, stream>>>(zb, woT, b_O, b_O, b_O,
                                                            nullptr, nullptr, out);
}

// Round 17
// 85.751 us; speedup vs baseline: 1.4597x; 1.1147x over previous
//
#include <hip/hip_runtime.h>

// Fused causal MHA on gfx950.  Pipeline (R16 = R15 + channel-camping fix):
//   K/V fragment loads in flash previously strode 4608B (K) and 4096B (V^T) per
//   row -> 16 concurrent line-requests aliasing the same L2 channel offset.
//   Now: K repacked per-head CONTIGUOUS khb[24][2048][64] (rows=128B lines,
//   consecutive); V^T repacked kv-chunk-tiled vtb[24][256][64][8] (vf loads =
//   4x256B coalesced segments).  Both written by the QKV GEMM epilogue.
//   Flash math/schedule identical to R13/R15 (shared-prefix pairs, fixed-max
//   softmax, swapped-operand MFMA).
//
// ws: xb/zb @0 (6291456) | qb @6291456 (6291456) | khb @12582912 (12582912)
//     vtb @25165824 (6291456) | wqkvT @31457280 (3538944) | woT @34996224
//     (1179648)   total 36175872 B (same as R15)

#define DEVINL __device__ __forceinline__

using bf16x8 = __attribute__((ext_vector_type(8))) __bf16;
using f32x4  = __attribute__((ext_vector_type(4))) float;

DEVINL unsigned short f32_bf16(float f) {
    unsigned u = __builtin_bit_cast(unsigned, f);
    return (unsigned short)((u + 0x7FFFu + ((u >> 16) & 1u)) >> 16);
}

DEVINL void gload16(const void* g, void* l) {
    __builtin_amdgcn_global_load_lds(
        (const __attribute__((address_space(1))) void*)g,
        (__attribute__((address_space(3))) void*)l, 16, 0, 0);
}

// ---------------- fused prep: convert + weight transposes ----------------
__global__ __launch_bounds__(256) void k_prep(const float* __restrict__ x,
                                              const float* __restrict__ Wq,
                                              const float* __restrict__ Wk,
                                              const float* __restrict__ Wv,
                                              const float* __restrict__ Wo,
                                              unsigned short* __restrict__ xb,
                                              unsigned short* __restrict__ wqkvT,
                                              unsigned short* __restrict__ woT) {
    __shared__ unsigned short tl[64][68];
    const int bid = blockIdx.x;
    const int t = threadIdx.x;
    if (bid < 3072) {
        int i = (bid * 256 + t) * 4;
        float4 v = *(const float4*)(x + i);
        ushort4 o;
        o.x = f32_bf16(v.x); o.y = f32_bf16(v.y); o.z = f32_bf16(v.z); o.w = f32_bf16(v.w);
        *(ushort4*)(xb + i) = o;
        return;
    }
    const int c = t & 63, r0 = t >> 6;
    if (bid < 3504) {
        const int sub = bid - 3072;          // 0..431
        const int tr = sub % 12, batch = sub / 12;   // batch 0..35
        const float* src = (batch < 12) ? Wq : (batch < 24) ? Wk : Wv;
        src += (size_t)(batch % 12) * 768 * 64;
        unsigned short* out = wqkvT + (size_t)batch * 64 * 768;
#pragma unroll
        for (int k = 0; k < 16; ++k) {
            int r = k * 4 + r0;
            tl[r][c] = f32_bf16(src[(size_t)(tr * 64 + r) * 64 + c]);
        }
        __syncthreads();
#pragma unroll
        for (int k = 0; k < 16; ++k) {
            int r2 = k * 4 + r0;
            out[(size_t)r2 * 768 + tr * 64 + c] = tl[c][r2];
        }
    } else {
        const int sub = bid - 3504;          // 0..143
        const int tr = sub % 12, tc = sub / 12;
#pragma unroll
        for (int k = 0; k < 16; ++k) {
            int r = k * 4 + r0;
            tl[r][c] = f32_bf16(Wo[(size_t)(tr * 64 + r) * 768 + tc * 64 + c]);
        }
        __syncthreads();
#pragma unroll
        for (int k = 0; k < 16; ++k) {
            int r2 = k * 4 + r0;
            woT[(size_t)(tc * 64 + r2) * 768 + tr * 64 + c] = tl[c][r2];
        }
    }
}

// ---------------- GEMM: C[4096][N] = A[4096][768] @ BT[N][768] + bias ----------------
// BK=64, 2-phase dbuf, source-chunk-XOR-swizzled gload_lds staging (R15).
// QKV=true epilogue routes: Q cols -> qb [4096][768] (scaled); K cols ->
// khb[bh][s][64] contiguous; V cols -> vtb[bh][s>>3][d][s&7] tiled.
template <int BM, int BN, bool QKV>
__global__ __launch_bounds__(256) void k_gemm(const unsigned short* __restrict__ A,
                                              const unsigned short* __restrict__ BT,
                                              const float* __restrict__ b0,
                                              const float* __restrict__ b1,
                                              const float* __restrict__ b2,
                                              unsigned short* __restrict__ qb,
                                              unsigned short* __restrict__ khb,
                                              unsigned short* __restrict__ vtb,
                                              float* __restrict__ outf) {
    constexpr int WM = BM / 2, WN = BN / 2, MR = WM / 16, NR = WN / 16;
    __shared__ alignas(16) unsigned short As[2][BM * 64];
    __shared__ alignas(16) unsigned short Bs[2][BN * 64];
    const int t = threadIdx.x;
    const int w = t >> 6, l = t & 63, lr = l & 15, lg = l >> 4;
    const int wr = (w >> 1) * WM, wc = (w & 1) * WN;
    const int m0 = blockIdx.y * BM;
    const int n0 = blockIdx.x * BN;

    auto stage = [&](int buf, int kt) {
        const int k0 = kt * 64;
#pragma unroll
        for (int i = 0; i < BM / 32; ++i) {
            const int s = i * 256 + t;
            const int row = s >> 3, cs = (s & 7) ^ (row & 7);
            gload16((const char*)A + ((size_t)(m0 + row) * 768 + k0) * 2 + cs * 16,
                    (char*)As[buf] + s * 16);
        }
#pragma unroll
        for (int i = 0; i < BN / 32; ++i) {
            const int s = i * 256 + t;
            const int row = s >> 3, cs = (s & 7) ^ (row & 7);
            gload16((const char*)BT + ((size_t)(n0 + row) * 768 + k0) * 2 + cs * 16,
                    (char*)Bs[buf] + s * 16);
        }
    };

    stage(0, 0);
    __syncthreads();

    f32x4 acc[MR][NR] = {};

    for (int kt = 0; kt < 12; ++kt) {
        const int cur = kt & 1;
        if (kt < 11) stage(cur ^ 1, kt + 1);

        bf16x8 af[MR][2], bfr[NR][2];
#pragma unroll
        for (int ri = 0; ri < MR; ++ri)
#pragma unroll
            for (int kk = 0; kk < 2; ++kk)
                af[ri][kk] = *(const bf16x8*)&As[cur][(wr + ri * 16 + lr) * 64 +
                                                     (((kk * 4 + lg) ^ (lr & 7)) << 3)];
#pragma unroll
        for (int cj = 0; cj < NR; ++cj)
#pragma unroll
            for (int kk = 0; kk < 2; ++kk)
                bfr[cj][kk] = *(const bf16x8*)&Bs[cur][(wc + cj * 16 + lr) * 64 +
                                                       (((kk * 4 + lg) ^ (lr & 7)) << 3)];
        __builtin_amdgcn_s_setprio(1);
#pragma unroll
        for (int ri = 0; ri < MR; ++ri)
#pragma unroll
            for (int cj = 0; cj < NR; ++cj) {
                acc[ri][cj] = __builtin_amdgcn_mfma_f32_16x16x32_bf16(
                    af[ri][0], bfr[cj][0], acc[ri][cj], 0, 0, 0);
                acc[ri][cj] = __builtin_amdgcn_mfma_f32_16x16x32_bf16(
                    af[ri][1], bfr[cj][1], acc[ri][cj], 0, 0, 0);
            }
        __builtin_amdgcn_s_setprio(0);
        __syncthreads();
    }

#pragma unroll
    for (int cj = 0; cj < NR; ++cj) {
        const int col = n0 + wc + cj * 16 + lr;
        if (QKV && col >= 1536) {
            // ---- V cols: vtb[bh][s>>3][d][s&7], ushort4 over e (s..s+3) ----
            const int vc = col - 1536;
            const float bv = b2[vc];
            const int hh = vc >> 6, dd = vc & 63;
#pragma unroll
            for (int ri = 0; ri < MR; ++ri) {
                const int row = m0 + wr + ri * 16 + lg * 4;   // s%8 in {0,4}
                const int bb = row >> 11, s = row & 2047;
                ushort4 pkv;
                pkv.x = f32_bf16(acc[ri][cj][0] + bv);
                pkv.y = f32_bf16(acc[ri][cj][1] + bv);
                pkv.z = f32_bf16(acc[ri][cj][2] + bv);
                pkv.w = f32_bf16(acc[ri][cj][3] + bv);
                *(ushort4*)(vtb + (size_t)(bb * 12 + hh) * 131072 +
                            (s >> 3) * 512 + dd * 8 + (s & 7)) = pkv;
            }
        } else if (QKV && col >= 768) {
            // ---- K cols: khb[bh][s][64] contiguous per head ----
            const int kc = col - 768;
            const float bv = b1[kc];
            const int hh = kc >> 6, dd = kc & 63;
#pragma unroll
            for (int ri = 0; ri < MR; ++ri)
#pragma unroll
                for (int e = 0; e < 4; ++e) {
                    const int row = m0 + wr + ri * 16 + lg * 4 + e;
                    const int bb = row >> 11, s = row & 2047;
                    khb[(size_t)(bb * 12 + hh) * 131072 + s * 64 + dd] =
                        f32_bf16(acc[ri][cj][e] + bv);
                }
        } else {
            const float bv = b0[col];
            const float scl = QKV ? 0.18033688011112042f : 1.0f;  // 0.125*log2e
#pragma unroll
            for (int ri = 0; ri < MR; ++ri)
#pragma unroll
                for (int e = 0; e < 4; ++e) {
                    const int row = m0 + wr + ri * 16 + lg * 4 + e;
                    const float v = (acc[ri][cj][e] + bv) * scl;
                    if (QKV) qb[(size_t)row * 768 + col] = f32_bf16(v);
                    else     outf[(size_t)row * 768 + col] = v;
                }
        }
    }
}

// ---------------- flash attention: shared-prefix paired items (R13 schedule) ----------
// grid (hb=24, p=32), 256 thr.  Item A: qiA=32+p; item B: qiB=31-p (same b,h).
// K from khb (contiguous 128B rows); V from tiled vtb (coalesced 256B segments).
#define WREG 8704
__global__ __launch_bounds__(256) void k_flash(const unsigned short* __restrict__ qb,
                                               const unsigned short* __restrict__ khb,
                                               const unsigned short* __restrict__ vtb,
                                               unsigned short* __restrict__ zb) {
    __shared__ alignas(16) char smem[4 * WREG + 1024];
    const int hb = blockIdx.x;              // 0..23
    const int h = hb % 12, b = hb / 12;
    const int p = blockIdx.y;               // 0..31
    const int qiA = 32 + p, qiB = 31 - p;
    const int q0A = qiA * 32, q0B = qiB * 32;
    const int nkvA = (qiA >> 1) + 1, nkvB = (qiB >> 1) + 1;
    const int t = threadIdx.x, w = t >> 6, l = t & 63, lr = l & 15, lg = l >> 4;

    char* p_w = smem + w * WREG;                       // P[q][kv] bf16, swizzled
    float* lldsA = (float*)(smem + 4 * WREG);          // [4][32]
    float* lldsB = (float*)(smem + 4 * WREG + 512);    // [4][32]

    const size_t qrowbase = (size_t)(b * 2048) * 768;
    bf16x8 qfA[2][2], qfB[2][2];
#pragma unroll
    for (int ri = 0; ri < 2; ++ri)
#pragma unroll
        for (int kk = 0; kk < 2; ++kk) {
            qfA[ri][kk] = *(const bf16x8*)(qb + qrowbase +
                                           (size_t)(q0A + ri * 16 + lr) * 768 +
                                           h * 64 + kk * 32 + lg * 8);
            qfB[ri][kk] = *(const bf16x8*)(qb + qrowbase +
                                           (size_t)(q0B + ri * 16 + lr) * 768 +
                                           h * 64 + kk * 32 + lg * 8);
        }

    f32x4 oA[2][4] = {}, oB[2][4] = {};
    float lsA[2] = {0.f, 0.f}, lsB[2] = {0.f, 0.f};

    const unsigned short* kh = khb + (size_t)(b * 12 + h) * 131072;  // [2048][64]
    const unsigned short* vt = vtb + (size_t)(b * 12 + h) * 131072;  // [256][64][8]

    {
        bf16x8 kf[4][2];
        auto loadK = [&](int kv0) {
#pragma unroll
            for (int cj = 0; cj < 4; ++cj)
#pragma unroll
                for (int kk = 0; kk < 2; ++kk)
                    kf[cj][kk] = *(const bf16x8*)(kh + (size_t)(kv0 + cj * 16 + lr) * 64 +
                                                  kk * 32 + lg * 8);
        };

        int kt = w;                // nkvA >= 17 > 4, so every wave has work
        loadK(kt * 64);
        do {
            const int kv0 = kt * 64;

            // V fragments issued FIRST -> latency covered by B+A compute.
            // Tiled layout: chunk = (kv0>>3)+kk*4+lg, addr = chunk*512 + d*8.
            bf16x8 vf[2][4];
#pragma unroll
            for (int kk = 0; kk < 2; ++kk)
#pragma unroll
                for (int dj = 0; dj < 4; ++dj)
                    vf[kk][dj] = *(const bf16x8*)(vt + (size_t)((kv0 >> 3) + kk * 4 + lg) * 512 +
                                                  (dj * 16 + lr) * 8);

            const f32x4 zz = {0.f, 0.f, 0.f, 0.f};

            // ================= item B (prefix rider) =================
            if (kt < nkvB) {
                f32x4 st[2][4];
                __builtin_amdgcn_s_setprio(1);
#pragma unroll
                for (int ri = 0; ri < 2; ++ri)
#pragma unroll
                    for (int cj = 0; cj < 4; ++cj) {
                        f32x4 a0 = __builtin_amdgcn_mfma_f32_16x16x32_bf16(kf[cj][0], qfB[ri][0], zz, 0, 0, 0);
                        st[ri][cj] = __builtin_amdgcn_mfma_f32_16x16x32_bf16(kf[cj][1], qfB[ri][1], a0, 0, 0, 0);
                    }
                __builtin_amdgcn_s_setprio(0);

                if (kt == nkvB - 1) {
#pragma unroll
                    for (int ri = 0; ri < 2; ++ri)
#pragma unroll
                        for (int cj = 0; cj < 4; ++cj)
#pragma unroll
                            for (int e = 0; e < 4; ++e) {
                                const int kvv = kv0 + cj * 16 + lg * 4 + e;
                                const int qq  = q0B + ri * 16 + lr;
                                if (kvv > qq) st[ri][cj][e] = -1e30f;
                            }
                }

#pragma unroll
                for (int ri = 0; ri < 2; ++ri) {
                    float ps = 0.f;
#pragma unroll
                    for (int cj = 0; cj < 4; ++cj)
#pragma unroll
                        for (int e = 0; e < 4; ++e) {
                            const float pv = __builtin_amdgcn_exp2f(st[ri][cj][e]);
                            st[ri][cj][e] = pv;
                            ps += pv;
                        }
                    lsB[ri] += ps;

                    const int row = ri * 16 + lr;
#pragma unroll
                    for (int cj = 0; cj < 4; ++cj) {
                        unsigned lo, hi;
                        asm("v_cvt_pk_bf16_f32 %0, %1, %2"
                            : "=v"(lo) : "v"(st[ri][cj][0]), "v"(st[ri][cj][1]));
                        asm("v_cvt_pk_bf16_f32 %0, %1, %2"
                            : "=v"(hi) : "v"(st[ri][cj][2]), "v"(st[ri][cj][3]));
                        const int gr = (cj * 2 + (lg >> 1)) ^ (lr & 7);
                        uint2 pk2; pk2.x = lo; pk2.y = hi;
                        *(uint2*)(p_w + row * 128 + gr * 16 + (lg & 1) * 8) = pk2;
                    }
                }

                asm volatile("" ::: "memory");

                __builtin_amdgcn_s_setprio(1);
#pragma unroll
                for (int kk = 0; kk < 2; ++kk)
#pragma unroll
                    for (int ri = 0; ri < 2; ++ri) {
                        const int row = ri * 16 + lr;
                        const int g = (kk * 4 + lg) ^ (lr & 7);
                        bf16x8 pa = *(const bf16x8*)(p_w + row * 128 + g * 16);
#pragma unroll
                        for (int dj = 0; dj < 4; ++dj)
                            oB[ri][dj] = __builtin_amdgcn_mfma_f32_16x16x32_bf16(
                                vf[kk][dj], pa, oB[ri][dj], 0, 0, 0);
                    }
                __builtin_amdgcn_s_setprio(0);

                asm volatile("" ::: "memory");
            }

            // ================= item A =================
            {
                f32x4 st[2][4];
                __builtin_amdgcn_s_setprio(1);
#pragma unroll
                for (int ri = 0; ri < 2; ++ri)
#pragma unroll
                    for (int cj = 0; cj < 4; ++cj) {
                        f32x4 a0 = __builtin_amdgcn_mfma_f32_16x16x32_bf16(kf[cj][0], qfA[ri][0], zz, 0, 0, 0);
                        st[ri][cj] = __builtin_amdgcn_mfma_f32_16x16x32_bf16(kf[cj][1], qfA[ri][1], a0, 0, 0, 0);
                    }
                __builtin_amdgcn_s_setprio(0);

                if (kt == nkvA - 1) {
#pragma unroll
                    for (int ri = 0; ri < 2; ++ri)
#pragma unroll
                        for (int cj = 0; cj < 4; ++cj)
#pragma unroll
                            for (int e = 0; e < 4; ++e) {
                                const int kvv = kv0 + cj * 16 + lg * 4 + e;
                                const int qq  = q0A + ri * 16 + lr;
                                if (kvv > qq) st[ri][cj][e] = -1e30f;
                            }
                }

#pragma unroll
                for (int ri = 0; ri < 2; ++ri) {
                    float ps = 0.f;
#pragma unroll
                    for (int cj = 0; cj < 4; ++cj)
#pragma unroll
                        for (int e = 0; e < 4; ++e) {
                            const float pv = __builtin_amdgcn_exp2f(st[ri][cj][e]);
                            st[ri][cj][e] = pv;
                            ps += pv;
                        }
                    lsA[ri] += ps;

                    const int row = ri * 16 + lr;
#pragma unroll
                    for (int cj = 0; cj < 4; ++cj) {
                        unsigned lo, hi;
                        asm("v_cvt_pk_bf16_f32 %0, %1, %2"
                            : "=v"(lo) : "v"(st[ri][cj][0]), "v"(st[ri][cj][1]));
                        asm("v_cvt_pk_bf16_f32 %0, %1, %2"
                            : "=v"(hi) : "v"(st[ri][cj][2]), "v"(st[ri][cj][3]));
                        const int gr = (cj * 2 + (lg >> 1)) ^ (lr & 7);
                        uint2 pk2; pk2.x = lo; pk2.y = hi;
                        *(uint2*)(p_w + row * 128 + gr * 16 + (lg & 1) * 8) = pk2;
                    }
                }

                asm volatile("" ::: "memory");

                // prefetch next K tile (kf dead after A-QK) under A's PV
                const bool more = (kt + 4 < nkvA);
                if (more) loadK(kv0 + 256);

                __builtin_amdgcn_s_setprio(1);
#pragma unroll
                for (int kk = 0; kk < 2; ++kk)
#pragma unroll
                    for (int ri = 0; ri < 2; ++ri) {
                        const int row = ri * 16 + lr;
                        const int g = (kk * 4 + lg) ^ (lr & 7);
                        bf16x8 pa = *(const bf16x8*)(p_w + row * 128 + g * 16);
#pragma unroll
                        for (int dj = 0; dj < 4; ++dj)
                            oA[ri][dj] = __builtin_amdgcn_mfma_f32_16x16x32_bf16(
                                vf[kk][dj], pa, oA[ri][dj], 0, 0, 0);
                    }
                __builtin_amdgcn_s_setprio(0);

                asm volatile("" ::: "memory");
            }

            kt += 4;
        } while (kt < nkvA);
    }

    // ---- row-total denominators for both items ----
#pragma unroll
    for (int ri = 0; ri < 2; ++ri) {
        float a = lsA[ri];
        a += __shfl_xor(a, 16); a += __shfl_xor(a, 32);
        lsA[ri] = a;
        float bsum = lsB[ri];
        bsum += __shfl_xor(bsum, 16); bsum += __shfl_xor(bsum, 32);
        lsB[ri] = bsum;
    }
    if (lg == 0) {
#pragma unroll
        for (int ri = 0; ri < 2; ++ri) {
            lldsA[w * 32 + ri * 16 + lr] = lsA[ri];
            lldsB[w * 32 + ri * 16 + lr] = lsB[ri];
        }
    }
    __syncthreads();   // loops done; P regions dead; llds complete

    // ---- merge item A, then item B (reusing scratch) ----
#pragma unroll
    for (int item = 0; item < 2; ++item) {
        const float* lld = item ? lldsB : lldsA;
        const int q0 = item ? q0B : q0A;
        float* o_w = (float*)(smem + w * WREG);  // [32][68] f32
#pragma unroll
        for (int ri = 0; ri < 2; ++ri) {
            const int row = ri * 16 + lr;
#pragma unroll
            for (int dj = 0; dj < 4; ++dj)
                *(f32x4*)&o_w[row * 68 + dj * 16 + lg * 4] = item ? oB[ri][dj] : oA[ri][dj];
        }
        __syncthreads();
        {
            const int row = w * 8 + (l >> 3);
            const int c0 = (l & 7) * 8;
            const float lt = lld[row] + lld[32 + row] + lld[64 + row] + lld[96 + row];
            const float inv = 1.0f / lt;
            ushort4 pk[2];
#pragma unroll
            for (int half = 0; half < 2; ++half) {
                unsigned short u[4];
#pragma unroll
                for (int k = 0; k < 4; ++k) {
                    float acc = 0.f;
#pragma unroll
                    for (int s = 0; s < 4; ++s)
                        acc += ((const float*)(smem + s * WREG))[row * 68 + c0 + half * 4 + k];
                    u[k] = f32_bf16(acc * inv);
                }
                pk[half] = make_ushort4(u[0], u[1], u[2], u[3]);
            }
            unsigned short* dst = zb + (size_t)(b * 2048 + q0 + row) * 768 + h * 64 + c0;
            *(ushort4*)dst = pk[0];
            *(ushort4*)(dst + 4) = pk[1];
        }
        __syncthreads();
    }
}

extern "C" void kernel_launch(void* const* d_in, const int* in_sizes, int n_in,
                              void* d_out, int out_size, void* d_ws, size_t ws_size,
                              hipStream_t stream) {
    (void)in_sizes; (void)n_in; (void)out_size; (void)ws_size;
    const float* x   = (const float*)d_in[0];
    const float* W_Q = (const float*)d_in[1];
    const float* W_K = (const float*)d_in[2];
    const float* W_V = (const float*)d_in[3];
    const float* b_Q = (const float*)d_in[4];
    const float* b_K = (const float*)d_in[5];
    const float* b_V = (const float*)d_in[6];
    const float* W_O = (const float*)d_in[7];
    const float* b_O = (const float*)d_in[8];
    float* out = (float*)d_out;

    char* ws = (char*)d_ws;
    unsigned short* xb    = (unsigned short*)(ws);
    unsigned short* qb    = (unsigned short*)(ws + 6291456);
    unsigned short* khb   = (unsigned short*)(ws + 12582912);
    unsigned short* vtb   = (unsigned short*)(ws + 25165824);
    unsigned short* wqkvT = (unsigned short*)(ws + 31457280);
    unsigned short* woT   = (unsigned short*)(ws + 34996224);
    unsigned short* zb    = xb;  // xb dead after the QKV GEMM

    k_prep<<<3648, 256, 0, stream>>>(x, W_Q, W_K, W_V, W_O, xb, wqkvT, woT);

    k_gemm<128, 64, true><<<dim3(36, 32), 256, 0, stream>>>(xb, wqkvT, b_Q, b_K, b_V,
                                                            qb, khb, vtb, nullptr);

    k_flash<<<dim3(24, 32), 256, 0, stream>>>(qb, khb, vtb, zb);

    k_gemm<64, 64, false><<<dim3(12, 64), 256, 0, stream>>>(zb, woT, b_O, b_O, b_O,
                                                            nullptr, nullptr, nullptr, out);
}